// Round 2
// baseline (3049.441 us; speedup 1.0000x reference)
//
#include <hip/hip_runtime.h>
#include <cstdint>

typedef unsigned int uint;
typedef unsigned short u16;

#define DEV __device__ __forceinline__

DEV float bf2f(u16 u) { return __uint_as_float(((uint)u) << 16); }
DEV u16 f2bf(float f) {
    uint x = __float_as_uint(f);
    return (u16)((x + 0x7fffu + ((x >> 16) & 1u)) >> 16);
}

// ---------------------------------------------------------------------------
// dtype detect: flag=1 if x buffer is bf16, 0 if f32.
// Samples 2048 u16 words at odd stride 37 (hits both halves of f32 words).
// bf16 data: ~100% have plausible exponent. f32 data: low halves are mantissa
// garbage (or exactly 0 for bf16-rounded f32) -> ~50-62% plausible.
// ---------------------------------------------------------------------------
__global__ void detect_kernel(const u16* __restrict__ x, int* __restrict__ flag)
{
    __shared__ int cnt[256];
    int t = threadIdx.x, good = 0;
#pragma unroll
    for (int i = 0; i < 8; ++i) {
        int s = t * 8 + i;
        u16 u = x[s * 37];           // max 2047*37=75739 < 98304 u16 (bf16 size)
        int e = (u >> 7) & 0xFF;
        good += (e >= 90 && e <= 150) ? 1 : 0;
    }
    cnt[t] = good;
    __syncthreads();
    if (t == 0) {
        int s = 0;
        for (int i = 0; i < 256; ++i) s += cnt[i];
        flag[0] = (s >= 1741) ? 1 : 0;   // 85% of 2048
    }
}

// ---------------------------------------------------------------------------
// convert all weight/param buffers to f32 in workspace (flag-branched).
// Order: w_in,b_in,w1,g1,be1,w2,g2,be2,w3,g3,be3,w4,g4,be4
// ---------------------------------------------------------------------------
struct InPtrs { const void* p[14]; };

__global__ void convert_weights(InPtrs ptrs, const int* __restrict__ flag,
                                float* __restrict__ cw)
{
    const int cnt[14] = {24, 8, 512, 32, 32, 4096, 64, 64, 8192, 64, 64, 16384, 128, 128};
    int g = blockIdx.x * 256 + threadIdx.x;
    if (g >= 29792) return;
    int isbf = flag[0];
    int idx = g, b = 0;
    while (idx >= cnt[b]) { idx -= cnt[b]; ++b; }
    cw[g] = isbf ? bf2f(((const u16*)ptrs.p[b])[idx])
                 : ((const float*)ptrs.p[b])[idx];
}

// ---------------------------------------------------------------------------
// prep: x (B,3,N) -> coorT (B,N,3) f32, f0 = w_in*x + b_in as (B,N,8) f32.
// ---------------------------------------------------------------------------
__global__ void prep_kernel(const void* __restrict__ xv, const int* __restrict__ flag,
                            const float* __restrict__ cw, float* __restrict__ coorT,
                            float* __restrict__ f0, int B, int N)
{
    int p = blockIdx.x * blockDim.x + threadIdx.x;
    if (p >= B * N) return;
    int isbf = flag[0];
    int b = p / N, n = p % N;
    float c0, c1, c2;
    if (isbf) {
        const u16* x = (const u16*)xv;
        c0 = bf2f(x[(b * 3 + 0) * N + n]);
        c1 = bf2f(x[(b * 3 + 1) * N + n]);
        c2 = bf2f(x[(b * 3 + 2) * N + n]);
    } else {
        const float* x = (const float*)xv;
        c0 = x[(b * 3 + 0) * N + n];
        c1 = x[(b * 3 + 1) * N + n];
        c2 = x[(b * 3 + 2) * N + n];
    }
    coorT[p * 3 + 0] = c0; coorT[p * 3 + 1] = c1; coorT[p * 3 + 2] = c2;
    const float* w_in = cw;
    const float* b_in = cw + 24;
#pragma unroll
    for (int o = 0; o < 8; ++o) {
        float v = b_in[o];
        v = fmaf(w_in[o * 3 + 0], c0, v);
        v = fmaf(w_in[o * 3 + 1], c1, v);
        v = fmaf(w_in[o * 3 + 2], c2, v);
        f0[(size_t)p * 8 + o] = v;
    }
}

// ---------------------------------------------------------------------------
// knn: for each query, 16 smallest d2 = (qq+kk) - 2*dot among Nk keys.
// Exact-RN ops (no FMA) to match numpy bit-for-bit; ties keep lowest index.
// ---------------------------------------------------------------------------
__global__ __launch_bounds__(256) void knn_kernel(
    const float* __restrict__ qxyz, const float* __restrict__ kxyz,
    int* __restrict__ idxout, int Nq, int Nk)
{
    __shared__ float4 kt[256];
    int b = blockIdx.y;
    int q = blockIdx.x * 256 + threadIdx.x;
    bool act = q < Nq;
    float qx = 0.f, qy = 0.f, qz = 0.f, qq = 0.f;
    if (act) {
        const float* qp = qxyz + (size_t)(b * Nq + q) * 3;
        qx = qp[0]; qy = qp[1]; qz = qp[2];
        qq = __fadd_rn(__fadd_rn(__fmul_rn(qx, qx), __fmul_rn(qy, qy)), __fmul_rn(qz, qz));
    }
    float bd[16]; int bi[16];
#pragma unroll
    for (int j = 0; j < 16; ++j) { bd[j] = 3.4e38f; bi[j] = 0; }

    for (int t0 = 0; t0 < Nk; t0 += 256) {
        {
            int i = threadIdx.x;
            const float* kp = kxyz + (size_t)(b * Nk + t0 + i) * 3;
            float kx = kp[0], ky = kp[1], kz = kp[2];
            float kn = __fadd_rn(__fadd_rn(__fmul_rn(kx, kx), __fmul_rn(ky, ky)), __fmul_rn(kz, kz));
            kt[i] = make_float4(kx, ky, kz, kn);
        }
        __syncthreads();
        if (act) {
            for (int i = 0; i < 256; ++i) {
                float4 kv = kt[i];
                float dot = __fadd_rn(__fadd_rn(__fmul_rn(qx, kv.x), __fmul_rn(qy, kv.y)),
                                      __fmul_rn(qz, kv.z));
                float d2 = __fsub_rn(__fadd_rn(qq, kv.w), __fmul_rn(2.0f, dot));
                if (d2 < bd[15]) {
                    int id = t0 + i;
#pragma unroll
                    for (int j = 15; j >= 1; --j) {
                        bool up  = (d2 < bd[j - 1]);
                        bool chg = (d2 < bd[j]);
                        if (chg) { bd[j] = up ? bd[j - 1] : d2; bi[j] = up ? bi[j - 1] : id; }
                    }
                    if (d2 < bd[0]) { bd[0] = d2; bi[0] = id; }
                }
            }
        }
        __syncthreads();
    }
    if (act) {
        int* op = idxout + (size_t)(b * Nq + q) * 16;
#pragma unroll
        for (int j = 0; j < 16; ++j) op[j] = bi[j];
    }
}

// ---------------------------------------------------------------------------
// fps: farthest point sampling; one block per batch; exact-RN distance math;
// argmax tie-break = lowest index. Indices structurally in [0,N).
// ---------------------------------------------------------------------------
template<int PTS>
__global__ __launch_bounds__(512) void fps_kernel(const float* __restrict__ xyz,
                                                  int* __restrict__ out, int N, int npoint)
{
    int b = blockIdx.x, tid = threadIdx.x;
    float px[PTS], py[PTS], pz[PTS], dist[PTS];
#pragma unroll
    for (int i = 0; i < PTS; ++i) {
        int p = tid + i * 512;
        const float* pp = xyz + (size_t)(b * N + p) * 3;
        px[i] = pp[0]; py[i] = pp[1]; pz[i] = pp[2];
        dist[i] = 1e10f;
    }
    __shared__ int s_far;
    __shared__ float s_bv[8];
    __shared__ int s_bi[8];
    if (tid == 0) s_far = 0;
    __syncthreads();

    for (int it = 0; it < npoint; ++it) {
        int far = s_far;
        if (tid == 0) out[b * npoint + it] = far;
        const float* cp = xyz + (size_t)(b * N + far) * 3;
        float cx = cp[0], cy = cp[1], cz = cp[2];
        float bv = -1.f; int bid = 0;
#pragma unroll
        for (int i = 0; i < PTS; ++i) {
            float dx = __fsub_rn(px[i], cx);
            float dy = __fsub_rn(py[i], cy);
            float dz = __fsub_rn(pz[i], cz);
            float d = __fadd_rn(__fadd_rn(__fmul_rn(dx, dx), __fmul_rn(dy, dy)), __fmul_rn(dz, dz));
            float nd = fminf(dist[i], d);
            dist[i] = nd;
            if (nd > bv) { bv = nd; bid = tid + i * 512; }
        }
#pragma unroll
        for (int m = 1; m < 64; m <<= 1) {
            float ov = __shfl_xor(bv, m);
            int   oi = __shfl_xor(bid, m);
            if (ov > bv || (ov == bv && oi < bid)) { bv = ov; bid = oi; }
        }
        __syncthreads();
        if ((tid & 63) == 0) { s_bv[tid >> 6] = bv; s_bi[tid >> 6] = bid; }
        __syncthreads();
        if (tid == 0) {
            float v = s_bv[0]; int ix = s_bi[0];
#pragma unroll
            for (int wv = 1; wv < 8; ++wv) {
                if (s_bv[wv] > v || (s_bv[wv] == v && s_bi[wv] < ix)) { v = s_bv[wv]; ix = s_bi[wv]; }
            }
            s_far = ix;
        }
        __syncthreads();
    }
}

// ---------------------------------------------------------------------------
// gather: coorD/fD[m] = coorS/fS[fidx[m]]
// ---------------------------------------------------------------------------
__global__ void gather_kernel(const float* __restrict__ coorS, const float* __restrict__ fS,
                              const int* __restrict__ fidx, float* __restrict__ coorD,
                              float* __restrict__ fD, int Ns, int M, int C)
{
    int b = blockIdx.y;
    int m = blockIdx.x * blockDim.x + threadIdx.x;
    if (m >= M) return;
    int j = fidx[b * M + m];
#pragma unroll
    for (int c = 0; c < 3; ++c)
        coorD[((size_t)b * M + m) * 3 + c] = coorS[((size_t)b * Ns + j) * 3 + c];
    for (int c = 0; c < C; ++c)
        fD[((size_t)b * M + m) * C + c] = fS[((size_t)b * Ns + j) * C + c];
}

// ---------------------------------------------------------------------------
// edge-conv stats: wave per query; lane per out-channel; edge feats in LDS.
// Deterministic fixed-order sums; partials[(b*4+g)*nchunk + chunk] = {s, ss}.
// ---------------------------------------------------------------------------
template<int C_IN, int C_OUT>
__global__ __launch_bounds__(256) void edge_conv_stats(
    const float* __restrict__ fq, const float* __restrict__ fk, const int* __restrict__ idx,
    const float* __restrict__ w, float* __restrict__ partials, int Nq, int Nk)
{
    constexpr int K = 16, E = 2 * C_IN, GC = C_OUT / 4;
    constexpr int ITERS = (C_OUT + 63) / 64;
    __shared__ alignas(16) float edge[4][K][E];
    __shared__ int nidx[4][K];
    __shared__ float gsum[4][4][2];

    int wave = threadIdx.x >> 6, lane = threadIdx.x & 63;
    int nqc = Nq >> 2;
    int b = blockIdx.y, chunk = blockIdx.x;
    int q = chunk * 4 + wave;

    const float* xqr = fq + (size_t)(b * Nq + q) * C_IN;
    if (lane < K) nidx[wave][lane] = idx[(size_t)(b * Nq + q) * K + lane];
    for (int t = lane; t < K * E; t += 64) {
        int k = t / E, c = t % E;
        int j = nidx[wave][k];
        float v;
        if (c < C_IN) v = fk[(size_t)(b * Nk + j) * C_IN + c] - xqr[c];
        else          v = xqr[c - C_IN];
        edge[wave][k][c] = v;
    }
    __syncthreads();

#pragma unroll
    for (int itr = 0; itr < ITERS; ++itr) {
        int oc = lane + 64 * itr;
        float s = 0.f, ss = 0.f;
        if (oc < C_OUT) {
            float v[K];
#pragma unroll
            for (int k2 = 0; k2 < K; ++k2) v[k2] = 0.f;
            const float* wr = w + (size_t)oc * E;
            for (int c = 0; c < E; c += 4) {
                float4 wv = *reinterpret_cast<const float4*>(wr + c);
#pragma unroll
                for (int k2 = 0; k2 < K; ++k2) {
                    const float4 e4 = *reinterpret_cast<const float4*>(&edge[wave][k2][c]);
                    v[k2] = fmaf(wv.x, e4.x, v[k2]);
                    v[k2] = fmaf(wv.y, e4.y, v[k2]);
                    v[k2] = fmaf(wv.z, e4.z, v[k2]);
                    v[k2] = fmaf(wv.w, e4.w, v[k2]);
                }
            }
#pragma unroll
            for (int k2 = 0; k2 < K; ++k2) { s += v[k2]; ss = fmaf(v[k2], v[k2], ss); }
        }
#pragma unroll
        for (int m2 = 1; m2 < GC; m2 <<= 1) { s += __shfl_xor(s, m2); ss += __shfl_xor(ss, m2); }
        if (oc < C_OUT && (oc & (GC - 1)) == 0) {
            gsum[wave][oc / GC][0] = s; gsum[wave][oc / GC][1] = ss;
        }
    }
    __syncthreads();
    if (threadIdx.x < 4) {
        int g = threadIdx.x;
        float s  = ((gsum[0][g][0] + gsum[1][g][0]) + gsum[2][g][0]) + gsum[3][g][0];
        float ss = ((gsum[0][g][1] + gsum[1][g][1]) + gsum[2][g][1]) + gsum[3][g][1];
        size_t pi = ((size_t)(b * 4 + g) * nqc + chunk) * 2;
        partials[pi] = s; partials[pi + 1] = ss;
    }
}

__global__ void gn_finalize(const float* __restrict__ partials, float* __restrict__ stats,
                            int nchunk, float inv_cnt)
{
    int i = threadIdx.x;
    if (i >= 32) return;
    float s = 0.f, ss = 0.f;
    for (int c = 0; c < nchunk; ++c) {
        s  += partials[((size_t)i * nchunk + c) * 2];
        ss += partials[((size_t)i * nchunk + c) * 2 + 1];
    }
    float mean = s * inv_cnt;
    float var = fmaf(-mean, mean, ss * inv_cnt);
    stats[i * 2] = mean;
    stats[i * 2 + 1] = 1.0f / sqrtf(var + 1e-5f);
}

// ---------------------------------------------------------------------------
// edge-conv apply: conv -> GN(normalize) -> leaky(0.2) -> max over K=16.
// ---------------------------------------------------------------------------
template<int C_IN, int C_OUT>
__global__ __launch_bounds__(256) void edge_conv_apply(
    const float* __restrict__ fq, const float* __restrict__ fk, const int* __restrict__ idx,
    const float* __restrict__ stats, const float* __restrict__ w,
    const float* __restrict__ gamma, const float* __restrict__ beta,
    float* __restrict__ outp, int Nq, int Nk)
{
    constexpr int K = 16, E = 2 * C_IN, GC = C_OUT / 4;
    constexpr int ITERS = (C_OUT + 63) / 64;
    __shared__ alignas(16) float edge[4][K][E];
    __shared__ int nidx[4][K];

    int wave = threadIdx.x >> 6, lane = threadIdx.x & 63;
    int b = blockIdx.y, chunk = blockIdx.x;
    int q = chunk * 4 + wave;

    const float* xqr = fq + (size_t)(b * Nq + q) * C_IN;
    if (lane < K) nidx[wave][lane] = idx[(size_t)(b * Nq + q) * K + lane];
    for (int t = lane; t < K * E; t += 64) {
        int k = t / E, c = t % E;
        int j = nidx[wave][k];
        float v;
        if (c < C_IN) v = fk[(size_t)(b * Nk + j) * C_IN + c] - xqr[c];
        else          v = xqr[c - C_IN];
        edge[wave][k][c] = v;
    }
    __syncthreads();

#pragma unroll
    for (int itr = 0; itr < ITERS; ++itr) {
        int oc = lane + 64 * itr;
        if (oc < C_OUT) {
            float v[K];
#pragma unroll
            for (int k2 = 0; k2 < K; ++k2) v[k2] = 0.f;
            const float* wr = w + (size_t)oc * E;
            for (int c = 0; c < E; c += 4) {
                float4 wv = *reinterpret_cast<const float4*>(wr + c);
#pragma unroll
                for (int k2 = 0; k2 < K; ++k2) {
                    const float4 e4 = *reinterpret_cast<const float4*>(&edge[wave][k2][c]);
                    v[k2] = fmaf(wv.x, e4.x, v[k2]);
                    v[k2] = fmaf(wv.y, e4.y, v[k2]);
                    v[k2] = fmaf(wv.z, e4.z, v[k2]);
                    v[k2] = fmaf(wv.w, e4.w, v[k2]);
                }
            }
            int g = oc / GC;
            float mean = stats[(b * 4 + g) * 2 + 0];
            float rstd = stats[(b * 4 + g) * 2 + 1];
            float ga = gamma[oc], be = beta[oc];
            float m = -3.4e38f;
#pragma unroll
            for (int k2 = 0; k2 < K; ++k2) {
                float y = fmaf((v[k2] - mean) * rstd, ga, be);
                y = (y >= 0.f) ? y : 0.2f * y;
                m = fmaxf(m, y);
            }
            outp[(size_t)(b * Nq + q) * C_OUT + oc] = m;
        }
    }
}

// ---------------------------------------------------------------------------
// write_out: out = [coor (B,3,128), f (B,128,128)], dtype per flag.
// ---------------------------------------------------------------------------
__global__ void write_out_kernel(const float* __restrict__ coor2T, const float* __restrict__ f4T,
                                 void* __restrict__ outv, const int* __restrict__ flag)
{
    int i = blockIdx.x * blockDim.x + threadIdx.x;
    if (i >= 134144) return;
    float v;
    if (i < 3072) {
        int b = i / 384, r = i % 384;
        int c = r / 128, n = r % 128;
        v = coor2T[((size_t)b * 128 + n) * 3 + c];
    } else {
        int jj = i - 3072;
        int b = jj / 16384, r = jj % 16384;
        int c = r / 128, qn = r % 128;
        v = f4T[((size_t)b * 128 + qn) * 128 + c];
    }
    if (flag[0]) ((u16*)outv)[i] = f2bf(v);
    else         ((float*)outv)[i] = v;
}

// ---------------------------------------------------------------------------
extern "C" void kernel_launch(void* const* d_in, const int* in_sizes, int n_in,
                              void* d_out, int out_size, void* d_ws, size_t ws_size,
                              hipStream_t stream)
{
    (void)in_sizes; (void)n_in; (void)out_size; (void)ws_size;
    constexpr int B = 8, N = 4096, M1 = 512, M2 = 128;

    float* fbase   = (float*)d_ws;
    float* coorT   = fbase;                  // 98304
    float* f0T     = coorT + 98304;          // 262144
    float* f1T     = f0T + 262144;           // 1048576
    float* f2T     = f1T + 1048576;          // 262144
    float* f3T     = f2T + 262144;           // 262144
    float* f4T     = f3T + 262144;           // 131072
    float* coor1T  = f4T + 131072;           // 12288
    float* coor2T  = coor1T + 12288;         // 3072
    float* fq2T    = coor2T + 3072;          // 131072
    float* fq4T    = fq2T + 131072;          // 65536
    float* statsb  = fq4T + 65536;           // 256
    float* partials= statsb + 256;           // 65536
    float* cw      = partials + 65536;       // 29792 (+pad to 29796)
    int* ibase = (int*)(cw + 29796);
    int* idx1 = ibase;                       // 524288
    int* idx2 = idx1 + 524288;               // 65536
    int* idx3 = idx2 + 65536;                // 65536
    int* idx4 = idx3 + 65536;                // 16384
    int* fps1 = idx4 + 16384;                // 4096
    int* fps2 = fps1 + 4096;                 // 1024
    int* flag = fps2 + 1024;                 // 1

    // converted-weight sub-pointers (prefix offsets)
    const float* w1c  = cw + 32;
    const float* g1c  = cw + 544;
    const float* be1c = cw + 576;
    const float* w2c  = cw + 608;
    const float* g2c  = cw + 4704;
    const float* be2c = cw + 4768;
    const float* w3c  = cw + 4832;
    const float* g3c  = cw + 13024;
    const float* be3c = cw + 13088;
    const float* w4c  = cw + 13152;
    const float* g4c  = cw + 29536;
    const float* be4c = cw + 29664;

    // stage -1: dtype detect + weight conversion
    detect_kernel<<<1, 256, 0, stream>>>((const u16*)d_in[0], flag);
    InPtrs ptrs;
    for (int i = 0; i < 14; ++i) ptrs.p[i] = d_in[i + 2];
    convert_weights<<<117, 256, 0, stream>>>(ptrs, flag, cw);

    // stage 0: prep
    prep_kernel<<<dim3((B * N + 255) / 256), 256, 0, stream>>>(d_in[0], flag, cw, coorT, f0T, B, N);

    // stage 1: knn(4096->4096), conv(16->32), GN(4), leaky, max
    knn_kernel<<<dim3(N / 256, B), 256, 0, stream>>>(coorT, coorT, idx1, N, N);
    edge_conv_stats<8, 32><<<dim3(N / 4, B), 256, 0, stream>>>(f0T, f0T, idx1, w1c, partials, N, N);
    gn_finalize<<<1, 32, 0, stream>>>(partials, statsb + 0, N / 4, 1.0f / (float)(N * 16 * 8));
    edge_conv_apply<8, 32><<<dim3(N / 4, B), 256, 0, stream>>>(f0T, f0T, idx1, statsb + 0, w1c, g1c, be1c, f1T, N, N);

    // fps 4096 -> 512 + gather
    fps_kernel<8><<<B, 512, 0, stream>>>(coorT, fps1, N, M1);
    gather_kernel<<<dim3((M1 + 255) / 256, B), 256, 0, stream>>>(coorT, f1T, fps1, coor1T, fq2T, N, M1, 32);

    // stage 2: knn(512 q -> 4096 k), conv(64->64)
    knn_kernel<<<dim3(M1 / 256, B), 256, 0, stream>>>(coor1T, coorT, idx2, M1, N);
    edge_conv_stats<32, 64><<<dim3(M1 / 4, B), 256, 0, stream>>>(fq2T, f1T, idx2, w2c, partials, M1, N);
    gn_finalize<<<1, 32, 0, stream>>>(partials, statsb + 64, M1 / 4, 1.0f / (float)(M1 * 16 * 16));
    edge_conv_apply<32, 64><<<dim3(M1 / 4, B), 256, 0, stream>>>(fq2T, f1T, idx2, statsb + 64, w2c, g2c, be2c, f2T, M1, N);

    // stage 3: knn(512->512), conv(128->64)
    knn_kernel<<<dim3(M1 / 256, B), 256, 0, stream>>>(coor1T, coor1T, idx3, M1, M1);
    edge_conv_stats<64, 64><<<dim3(M1 / 4, B), 256, 0, stream>>>(f2T, f2T, idx3, w3c, partials, M1, M1);
    gn_finalize<<<1, 32, 0, stream>>>(partials, statsb + 128, M1 / 4, 1.0f / (float)(M1 * 16 * 16));
    edge_conv_apply<64, 64><<<dim3(M1 / 4, B), 256, 0, stream>>>(f2T, f2T, idx3, statsb + 128, w3c, g3c, be3c, f3T, M1, M1);

    // fps 512 -> 128 + gather
    fps_kernel<1><<<B, 512, 0, stream>>>(coor1T, fps2, M1, M2);
    gather_kernel<<<dim3(1, B), 256, 0, stream>>>(coor1T, f3T, fps2, coor2T, fq4T, M1, M2, 64);

    // stage 4: knn(128 q -> 512 k), conv(128->128)
    knn_kernel<<<dim3(1, B), 256, 0, stream>>>(coor2T, coor1T, idx4, M2, M1);
    edge_conv_stats<64, 128><<<dim3(M2 / 4, B), 256, 0, stream>>>(fq4T, f3T, idx4, w4c, partials, M2, M1);
    gn_finalize<<<1, 32, 0, stream>>>(partials, statsb + 192, M2 / 4, 1.0f / (float)(M2 * 16 * 32));
    edge_conv_apply<64, 128><<<dim3(M2 / 4, B), 256, 0, stream>>>(fq4T, f3T, idx4, statsb + 192, w4c, g4c, be4c, f4T, M2, M1);

    // output
    write_out_kernel<<<(134144 + 255) / 256, 256, 0, stream>>>(coor2T, f4T, d_out, flag);
}

// Round 3
// 1844.656 us; speedup vs baseline: 1.6531x; 1.6531x over previous
//
#include <hip/hip_runtime.h>
#include <cstdint>

typedef unsigned int uint;
typedef unsigned short u16;

#define DEV __device__ __forceinline__

DEV float bf2f(u16 u) { return __uint_as_float(((uint)u) << 16); }
DEV u16 f2bf(float f) {
    uint x = __float_as_uint(f);
    return (u16)((x + 0x7fffu + ((x >> 16) & 1u)) >> 16);
}

// ---------------------------------------------------------------------------
// dtype detect: flag=1 if x buffer is bf16, 0 if f32.
// ---------------------------------------------------------------------------
__global__ void detect_kernel(const u16* __restrict__ x, int* __restrict__ flag)
{
    __shared__ int cnt[256];
    int t = threadIdx.x, good = 0;
#pragma unroll
    for (int i = 0; i < 8; ++i) {
        int s = t * 8 + i;
        u16 u = x[s * 37];
        int e = (u >> 7) & 0xFF;
        good += (e >= 90 && e <= 150) ? 1 : 0;
    }
    cnt[t] = good;
    __syncthreads();
    if (t == 0) {
        int s = 0;
        for (int i = 0; i < 256; ++i) s += cnt[i];
        flag[0] = (s >= 1741) ? 1 : 0;
    }
}

// ---------------------------------------------------------------------------
// convert all weight/param buffers to f32 in workspace (flag-branched).
// ---------------------------------------------------------------------------
struct InPtrs { const void* p[14]; };

__global__ void convert_weights(InPtrs ptrs, const int* __restrict__ flag,
                                float* __restrict__ cw)
{
    const int cnt[14] = {24, 8, 512, 32, 32, 4096, 64, 64, 8192, 64, 64, 16384, 128, 128};
    int g = blockIdx.x * 256 + threadIdx.x;
    if (g >= 29792) return;
    int isbf = flag[0];
    int idx = g, b = 0;
    while (idx >= cnt[b]) { idx -= cnt[b]; ++b; }
    cw[g] = isbf ? bf2f(((const u16*)ptrs.p[b])[idx])
                 : ((const float*)ptrs.p[b])[idx];
}

// ---------------------------------------------------------------------------
// prep: x (B,3,N) -> coorT (B,N,3) f32, f0 = w_in*x + b_in as (B,N,8) f32.
// ---------------------------------------------------------------------------
__global__ void prep_kernel(const void* __restrict__ xv, const int* __restrict__ flag,
                            const float* __restrict__ cw, float* __restrict__ coorT,
                            float* __restrict__ f0, int B, int N)
{
    int p = blockIdx.x * blockDim.x + threadIdx.x;
    if (p >= B * N) return;
    int isbf = flag[0];
    int b = p / N, n = p % N;
    float c0, c1, c2;
    if (isbf) {
        const u16* x = (const u16*)xv;
        c0 = bf2f(x[(b * 3 + 0) * N + n]);
        c1 = bf2f(x[(b * 3 + 1) * N + n]);
        c2 = bf2f(x[(b * 3 + 2) * N + n]);
    } else {
        const float* x = (const float*)xv;
        c0 = x[(b * 3 + 0) * N + n];
        c1 = x[(b * 3 + 1) * N + n];
        c2 = x[(b * 3 + 2) * N + n];
    }
    coorT[p * 3 + 0] = c0; coorT[p * 3 + 1] = c1; coorT[p * 3 + 2] = c2;
    const float* w_in = cw;
    const float* b_in = cw + 24;
#pragma unroll
    for (int o = 0; o < 8; ++o) {
        float v = b_in[o];
        v = fmaf(w_in[o * 3 + 0], c0, v);
        v = fmaf(w_in[o * 3 + 1], c1, v);
        v = fmaf(w_in[o * 3 + 2], c2, v);
        f0[(size_t)p * 8 + o] = v;
    }
}

// ---------------------------------------------------------------------------
// knn: 64 queries per block; 4 waves split each 256-key tile 4-ways; partial
// top-16 lists lex-merged (d2, idx) in LDS. Exact-RN ops; set identical to
// full scan incl. lowest-index tie-break.
// ---------------------------------------------------------------------------
__global__ __launch_bounds__(256) void knn_kernel(
    const float* __restrict__ qxyz, const float* __restrict__ kxyz,
    int* __restrict__ idxout, int Nq, int Nk)
{
    __shared__ float4 kt[256];
    __shared__ float2 mrg[4][64][16];
    int b = blockIdx.y;
    int qloc = threadIdx.x & 63;
    int wave = threadIdx.x >> 6;
    int q = blockIdx.x * 64 + qloc;
    bool act = q < Nq;

    float qx = 0.f, qy = 0.f, qz = 0.f, qq = 0.f;
    if (act) {
        const float* qp = qxyz + (size_t)(b * Nq + q) * 3;
        qx = qp[0]; qy = qp[1]; qz = qp[2];
        qq = __fadd_rn(__fadd_rn(__fmul_rn(qx, qx), __fmul_rn(qy, qy)), __fmul_rn(qz, qz));
    }
    float bd[16]; int bi[16];
#pragma unroll
    for (int j = 0; j < 16; ++j) { bd[j] = 3.4e38f; bi[j] = 0; }

    for (int t0 = 0; t0 < Nk; t0 += 256) {
        {
            int i = threadIdx.x;
            const float* kp = kxyz + (size_t)(b * Nk + t0 + i) * 3;
            float kx = kp[0], ky = kp[1], kz = kp[2];
            float kn = __fadd_rn(__fadd_rn(__fmul_rn(kx, kx), __fmul_rn(ky, ky)), __fmul_rn(kz, kz));
            kt[i] = make_float4(kx, ky, kz, kn);
        }
        __syncthreads();
        if (act) {
            for (int i2 = 0; i2 < 64; ++i2) {
                int ii = wave * 64 + i2;
                float4 kv = kt[ii];
                float dot = __fadd_rn(__fadd_rn(__fmul_rn(qx, kv.x), __fmul_rn(qy, kv.y)),
                                      __fmul_rn(qz, kv.z));
                float d2 = __fsub_rn(__fadd_rn(qq, kv.w), __fmul_rn(2.0f, dot));
                if (d2 < bd[15]) {
                    int id = t0 + ii;
#pragma unroll
                    for (int j = 15; j >= 1; --j) {
                        bool up  = (d2 < bd[j - 1]);
                        bool chg = (d2 < bd[j]);
                        if (chg) { bd[j] = up ? bd[j - 1] : d2; bi[j] = up ? bi[j - 1] : id; }
                    }
                    if (d2 < bd[0]) { bd[0] = d2; bi[0] = id; }
                }
            }
        }
        __syncthreads();
    }
#pragma unroll
    for (int j = 0; j < 16; ++j)
        mrg[wave][qloc][j] = make_float2(bd[j], __int_as_float(bi[j]));
    __syncthreads();

    if (threadIdx.x < 64) {
        int qm = threadIdx.x;
        int qg = blockIdx.x * 64 + qm;
        if (qg < Nq) {
            int* op = idxout + (size_t)(b * Nq + qg) * 16;
            int p0 = 0, p1 = 0, p2 = 0, p3 = 0;
#pragma unroll 1
            for (int j = 0; j < 16; ++j) {
                float2 h0 = mrg[0][qm][p0], h1 = mrg[1][qm][p1];
                float2 h2 = mrg[2][qm][p2], h3 = mrg[3][qm][p3];
                float bdv = h0.x; int biv = __float_as_int(h0.y); int w_ = 0;
                int i1 = __float_as_int(h1.y);
                if (h1.x < bdv || (h1.x == bdv && i1 < biv)) { bdv = h1.x; biv = i1; w_ = 1; }
                int i2v = __float_as_int(h2.y);
                if (h2.x < bdv || (h2.x == bdv && i2v < biv)) { bdv = h2.x; biv = i2v; w_ = 2; }
                int i3 = __float_as_int(h3.y);
                if (h3.x < bdv || (h3.x == bdv && i3 < biv)) { bdv = h3.x; biv = i3; w_ = 3; }
                op[j] = biv;
                p0 += (w_ == 0); p1 += (w_ == 1); p2 += (w_ == 2); p3 += (w_ == 3);
            }
        }
    }
}

// ---------------------------------------------------------------------------
// fps: point cloud staged in LDS (centroid broadcast, no global re-read);
// coords+dist in registers; ONE barrier per iteration (parity-double-buffered
// reduce slots + redundant cross-wave winner computation in all threads).
// Exact-RN math; argmax tie-break lowest index.
// ---------------------------------------------------------------------------
template<int PTS, int N>
__global__ __launch_bounds__(512) void fps_kernel(const float* __restrict__ xyz,
                                                  int* __restrict__ out, int npoint)
{
    __shared__ float sx[N], sy[N], sz[N];
    __shared__ float rv[2][8];
    __shared__ int   ri[2][8];
    int b = blockIdx.x, tid = threadIdx.x;
    int wave = tid >> 6, lane = tid & 63;
    float px[PTS], py[PTS], pz[PTS], dist[PTS];
#pragma unroll
    for (int i = 0; i < PTS; ++i) {
        int p = tid + i * 512;
        const float* pp = xyz + (size_t)(b * N + p) * 3;
        float x0 = pp[0], y0 = pp[1], z0 = pp[2];
        px[i] = x0; py[i] = y0; pz[i] = z0;
        sx[p] = x0; sy[p] = y0; sz[p] = z0;
        dist[i] = 1e10f;
    }
    __syncthreads();
    int far = 0;
    for (int it = 0; it < npoint; ++it) {
        if (tid == 0) out[b * npoint + it] = far;
        float cx = sx[far], cy = sy[far], cz = sz[far];
        float bv = -1.f; int bid = 0;
#pragma unroll
        for (int i = 0; i < PTS; ++i) {
            float dx = __fsub_rn(px[i], cx);
            float dy = __fsub_rn(py[i], cy);
            float dz = __fsub_rn(pz[i], cz);
            float d = __fadd_rn(__fadd_rn(__fmul_rn(dx, dx), __fmul_rn(dy, dy)), __fmul_rn(dz, dz));
            float nd = fminf(dist[i], d);
            dist[i] = nd;
            if (nd > bv) { bv = nd; bid = tid + i * 512; }
        }
#pragma unroll
        for (int m = 1; m < 64; m <<= 1) {
            float ov = __shfl_xor(bv, m);
            int   oi = __shfl_xor(bid, m);
            if (ov > bv || (ov == bv && oi < bid)) { bv = ov; bid = oi; }
        }
        int par = it & 1;
        if (lane == 0) { rv[par][wave] = bv; ri[par][wave] = bid; }
        __syncthreads();
        {
            float v = rv[par][0]; int ix = ri[par][0];
#pragma unroll
            for (int wv = 1; wv < (N / 512 >= 1 ? 8 : 8); ++wv) {
                float ovv = rv[par][wv]; int oii = ri[par][wv];
                if (ovv > v || (ovv == v && oii < ix)) { v = ovv; ix = oii; }
            }
            far = ix;
        }
    }
}

// ---------------------------------------------------------------------------
// gather: coorD/fD[m] = coorS/fS[fidx[m]]
// ---------------------------------------------------------------------------
__global__ void gather_kernel(const float* __restrict__ coorS, const float* __restrict__ fS,
                              const int* __restrict__ fidx, float* __restrict__ coorD,
                              float* __restrict__ fD, int Ns, int M, int C)
{
    int b = blockIdx.y;
    int m = blockIdx.x * blockDim.x + threadIdx.x;
    if (m >= M) return;
    int j = fidx[b * M + m];
#pragma unroll
    for (int c = 0; c < 3; ++c)
        coorD[((size_t)b * M + m) * 3 + c] = coorS[((size_t)b * Ns + j) * 3 + c];
    for (int c = 0; c < C; ++c)
        fD[((size_t)b * M + m) * C + c] = fS[((size_t)b * Ns + j) * C + c];
}

// ---------------------------------------------------------------------------
// edge-conv stats: wave per query; lane per out-channel; edge feats in LDS.
// ---------------------------------------------------------------------------
template<int C_IN, int C_OUT>
__global__ __launch_bounds__(256) void edge_conv_stats(
    const float* __restrict__ fq, const float* __restrict__ fk, const int* __restrict__ idx,
    const float* __restrict__ w, float* __restrict__ partials, int Nq, int Nk)
{
    constexpr int K = 16, E = 2 * C_IN, GC = C_OUT / 4;
    constexpr int ITERS = (C_OUT + 63) / 64;
    __shared__ alignas(16) float edge[4][K][E];
    __shared__ int nidx[4][K];
    __shared__ float gsum[4][4][2];

    int wave = threadIdx.x >> 6, lane = threadIdx.x & 63;
    int nqc = Nq >> 2;
    int b = blockIdx.y, chunk = blockIdx.x;
    int q = chunk * 4 + wave;

    const float* xqr = fq + (size_t)(b * Nq + q) * C_IN;
    if (lane < K) nidx[wave][lane] = idx[(size_t)(b * Nq + q) * K + lane];
    for (int t = lane; t < K * E; t += 64) {
        int k = t / E, c = t % E;
        int j = nidx[wave][k];
        float v;
        if (c < C_IN) v = fk[(size_t)(b * Nk + j) * C_IN + c] - xqr[c];
        else          v = xqr[c - C_IN];
        edge[wave][k][c] = v;
    }
    __syncthreads();

#pragma unroll
    for (int itr = 0; itr < ITERS; ++itr) {
        int oc = lane + 64 * itr;
        float s = 0.f, ss = 0.f;
        if (oc < C_OUT) {
            float v[K];
#pragma unroll
            for (int k2 = 0; k2 < K; ++k2) v[k2] = 0.f;
            const float* wr = w + (size_t)oc * E;
            for (int c = 0; c < E; c += 4) {
                float4 wv = *reinterpret_cast<const float4*>(wr + c);
#pragma unroll
                for (int k2 = 0; k2 < K; ++k2) {
                    const float4 e4 = *reinterpret_cast<const float4*>(&edge[wave][k2][c]);
                    v[k2] = fmaf(wv.x, e4.x, v[k2]);
                    v[k2] = fmaf(wv.y, e4.y, v[k2]);
                    v[k2] = fmaf(wv.z, e4.z, v[k2]);
                    v[k2] = fmaf(wv.w, e4.w, v[k2]);
                }
            }
#pragma unroll
            for (int k2 = 0; k2 < K; ++k2) { s += v[k2]; ss = fmaf(v[k2], v[k2], ss); }
        }
#pragma unroll
        for (int m2 = 1; m2 < GC; m2 <<= 1) { s += __shfl_xor(s, m2); ss += __shfl_xor(ss, m2); }
        if (oc < C_OUT && (oc & (GC - 1)) == 0) {
            gsum[wave][oc / GC][0] = s; gsum[wave][oc / GC][1] = ss;
        }
    }
    __syncthreads();
    if (threadIdx.x < 4) {
        int g = threadIdx.x;
        float s  = ((gsum[0][g][0] + gsum[1][g][0]) + gsum[2][g][0]) + gsum[3][g][0];
        float ss = ((gsum[0][g][1] + gsum[1][g][1]) + gsum[2][g][1]) + gsum[3][g][1];
        size_t pi = ((size_t)(b * 4 + g) * nqc + chunk) * 2;
        partials[pi] = s; partials[pi + 1] = ss;
    }
}

// gn_finalize: 256 threads, 8 lanes per (b,g)-stat, shuffle reduce.
__global__ void gn_finalize(const float* __restrict__ partials, float* __restrict__ stats,
                            int nchunk, float inv_cnt)
{
    int i = threadIdx.x >> 3;       // stat id 0..31
    int sl = threadIdx.x & 7;       // sub-lane
    float s = 0.f, ss = 0.f;
    for (int c = sl; c < nchunk; c += 8) {
        s  += partials[((size_t)i * nchunk + c) * 2];
        ss += partials[((size_t)i * nchunk + c) * 2 + 1];
    }
#pragma unroll
    for (int m = 1; m < 8; m <<= 1) { s += __shfl_xor(s, m); ss += __shfl_xor(ss, m); }
    if (sl == 0) {
        float mean = s * inv_cnt;
        float var = fmaf(-mean, mean, ss * inv_cnt);
        stats[i * 2] = mean;
        stats[i * 2 + 1] = 1.0f / sqrtf(var + 1e-5f);
    }
}

// ---------------------------------------------------------------------------
// edge-conv apply: conv -> GN(normalize) -> leaky(0.2) -> max over K=16.
// ---------------------------------------------------------------------------
template<int C_IN, int C_OUT>
__global__ __launch_bounds__(256) void edge_conv_apply(
    const float* __restrict__ fq, const float* __restrict__ fk, const int* __restrict__ idx,
    const float* __restrict__ stats, const float* __restrict__ w,
    const float* __restrict__ gamma, const float* __restrict__ beta,
    float* __restrict__ outp, int Nq, int Nk)
{
    constexpr int K = 16, E = 2 * C_IN, GC = C_OUT / 4;
    constexpr int ITERS = (C_OUT + 63) / 64;
    __shared__ alignas(16) float edge[4][K][E];
    __shared__ int nidx[4][K];

    int wave = threadIdx.x >> 6, lane = threadIdx.x & 63;
    int b = blockIdx.y, chunk = blockIdx.x;
    int q = chunk * 4 + wave;

    const float* xqr = fq + (size_t)(b * Nq + q) * C_IN;
    if (lane < K) nidx[wave][lane] = idx[(size_t)(b * Nq + q) * K + lane];
    for (int t = lane; t < K * E; t += 64) {
        int k = t / E, c = t % E;
        int j = nidx[wave][k];
        float v;
        if (c < C_IN) v = fk[(size_t)(b * Nk + j) * C_IN + c] - xqr[c];
        else          v = xqr[c - C_IN];
        edge[wave][k][c] = v;
    }
    __syncthreads();

#pragma unroll
    for (int itr = 0; itr < ITERS; ++itr) {
        int oc = lane + 64 * itr;
        if (oc < C_OUT) {
            float v[K];
#pragma unroll
            for (int k2 = 0; k2 < K; ++k2) v[k2] = 0.f;
            const float* wr = w + (size_t)oc * E;
            for (int c = 0; c < E; c += 4) {
                float4 wv = *reinterpret_cast<const float4*>(wr + c);
#pragma unroll
                for (int k2 = 0; k2 < K; ++k2) {
                    const float4 e4 = *reinterpret_cast<const float4*>(&edge[wave][k2][c]);
                    v[k2] = fmaf(wv.x, e4.x, v[k2]);
                    v[k2] = fmaf(wv.y, e4.y, v[k2]);
                    v[k2] = fmaf(wv.z, e4.z, v[k2]);
                    v[k2] = fmaf(wv.w, e4.w, v[k2]);
                }
            }
            int g = oc / GC;
            float mean = stats[(b * 4 + g) * 2 + 0];
            float rstd = stats[(b * 4 + g) * 2 + 1];
            float ga = gamma[oc], be = beta[oc];
            float m = -3.4e38f;
#pragma unroll
            for (int k2 = 0; k2 < K; ++k2) {
                float y = fmaf((v[k2] - mean) * rstd, ga, be);
                y = (y >= 0.f) ? y : 0.2f * y;
                m = fmaxf(m, y);
            }
            outp[(size_t)(b * Nq + q) * C_OUT + oc] = m;
        }
    }
}

// ---------------------------------------------------------------------------
// write_out: out = [coor (B,3,128), f (B,128,128)], dtype per flag.
// ---------------------------------------------------------------------------
__global__ void write_out_kernel(const float* __restrict__ coor2T, const float* __restrict__ f4T,
                                 void* __restrict__ outv, const int* __restrict__ flag)
{
    int i = blockIdx.x * blockDim.x + threadIdx.x;
    if (i >= 134144) return;
    float v;
    if (i < 3072) {
        int b = i / 384, r = i % 384;
        int c = r / 128, n = r % 128;
        v = coor2T[((size_t)b * 128 + n) * 3 + c];
    } else {
        int jj = i - 3072;
        int b = jj / 16384, r = jj % 16384;
        int c = r / 128, qn = r % 128;
        v = f4T[((size_t)b * 128 + qn) * 128 + c];
    }
    if (flag[0]) ((u16*)outv)[i] = f2bf(v);
    else         ((float*)outv)[i] = v;
}

// ---------------------------------------------------------------------------
extern "C" void kernel_launch(void* const* d_in, const int* in_sizes, int n_in,
                              void* d_out, int out_size, void* d_ws, size_t ws_size,
                              hipStream_t stream)
{
    (void)in_sizes; (void)n_in; (void)out_size; (void)ws_size;
    constexpr int B = 8, N = 4096, M1 = 512, M2 = 128;

    float* fbase   = (float*)d_ws;
    float* coorT   = fbase;                  // 98304
    float* f0T     = coorT + 98304;          // 262144
    float* f1T     = f0T + 262144;           // 1048576
    float* f2T     = f1T + 1048576;          // 262144
    float* f3T     = f2T + 262144;           // 262144
    float* f4T     = f3T + 262144;           // 131072
    float* coor1T  = f4T + 131072;           // 12288
    float* coor2T  = coor1T + 12288;         // 3072
    float* fq2T    = coor2T + 3072;          // 131072
    float* fq4T    = fq2T + 131072;          // 65536
    float* statsb  = fq4T + 65536;           // 256
    float* partials= statsb + 256;           // 65536
    float* cw      = partials + 65536;       // 29792 (+pad to 29796)
    int* ibase = (int*)(cw + 29796);
    int* idx1 = ibase;                       // 524288
    int* idx2 = idx1 + 524288;               // 65536
    int* idx3 = idx2 + 65536;                // 65536
    int* idx4 = idx3 + 65536;                // 16384
    int* fps1 = idx4 + 16384;                // 4096
    int* fps2 = fps1 + 4096;                 // 1024
    int* flag = fps2 + 1024;                 // 1

    const float* w1c  = cw + 32;
    const float* g1c  = cw + 544;
    const float* be1c = cw + 576;
    const float* w2c  = cw + 608;
    const float* g2c  = cw + 4704;
    const float* be2c = cw + 4768;
    const float* w3c  = cw + 4832;
    const float* g3c  = cw + 13024;
    const float* be3c = cw + 13088;
    const float* w4c  = cw + 13152;
    const float* g4c  = cw + 29536;
    const float* be4c = cw + 29664;

    detect_kernel<<<1, 256, 0, stream>>>((const u16*)d_in[0], flag);
    InPtrs ptrs;
    for (int i = 0; i < 14; ++i) ptrs.p[i] = d_in[i + 2];
    convert_weights<<<117, 256, 0, stream>>>(ptrs, flag, cw);

    prep_kernel<<<dim3((B * N + 255) / 256), 256, 0, stream>>>(d_in[0], flag, cw, coorT, f0T, B, N);

    // stage 1
    knn_kernel<<<dim3(N / 64, B), 256, 0, stream>>>(coorT, coorT, idx1, N, N);
    edge_conv_stats<8, 32><<<dim3(N / 4, B), 256, 0, stream>>>(f0T, f0T, idx1, w1c, partials, N, N);
    gn_finalize<<<1, 256, 0, stream>>>(partials, statsb + 0, N / 4, 1.0f / (float)(N * 16 * 8));
    edge_conv_apply<8, 32><<<dim3(N / 4, B), 256, 0, stream>>>(f0T, f0T, idx1, statsb + 0, w1c, g1c, be1c, f1T, N, N);

    // fps 4096 -> 512 + gather
    fps_kernel<8, 4096><<<B, 512, 0, stream>>>(coorT, fps1, M1);
    gather_kernel<<<dim3((M1 + 255) / 256, B), 256, 0, stream>>>(coorT, f1T, fps1, coor1T, fq2T, N, M1, 32);

    // stage 2
    knn_kernel<<<dim3(M1 / 64, B), 256, 0, stream>>>(coor1T, coorT, idx2, M1, N);
    edge_conv_stats<32, 64><<<dim3(M1 / 4, B), 256, 0, stream>>>(fq2T, f1T, idx2, w2c, partials, M1, N);
    gn_finalize<<<1, 256, 0, stream>>>(partials, statsb + 64, M1 / 4, 1.0f / (float)(M1 * 16 * 16));
    edge_conv_apply<32, 64><<<dim3(M1 / 4, B), 256, 0, stream>>>(fq2T, f1T, idx2, statsb + 64, w2c, g2c, be2c, f2T, M1, N);

    // stage 3
    knn_kernel<<<dim3(M1 / 64, B), 256, 0, stream>>>(coor1T, coor1T, idx3, M1, M1);
    edge_conv_stats<64, 64><<<dim3(M1 / 4, B), 256, 0, stream>>>(f2T, f2T, idx3, w3c, partials, M1, M1);
    gn_finalize<<<1, 256, 0, stream>>>(partials, statsb + 128, M1 / 4, 1.0f / (float)(M1 * 16 * 16));
    edge_conv_apply<64, 64><<<dim3(M1 / 4, B), 256, 0, stream>>>(f2T, f2T, idx3, statsb + 128, w3c, g3c, be3c, f3T, M1, M1);

    // fps 512 -> 128 + gather
    fps_kernel<1, 512><<<B, 512, 0, stream>>>(coor1T, fps2, M2);
    gather_kernel<<<dim3(1, B), 256, 0, stream>>>(coor1T, f3T, fps2, coor2T, fq4T, M1, M2, 64);

    // stage 4
    knn_kernel<<<dim3((M2 + 63) / 64, B), 256, 0, stream>>>(coor2T, coor1T, idx4, M2, M1);
    edge_conv_stats<64, 128><<<dim3(M2 / 4, B), 256, 0, stream>>>(fq4T, f3T, idx4, w4c, partials, M2, M1);
    gn_finalize<<<1, 256, 0, stream>>>(partials, statsb + 192, M2 / 4, 1.0f / (float)(M2 * 16 * 32));
    edge_conv_apply<64, 128><<<dim3(M2 / 4, B), 256, 0, stream>>>(fq4T, f3T, idx4, statsb + 192, w4c, g4c, be4c, f4T, M2, M1);

    write_out_kernel<<<(134144 + 255) / 256, 256, 0, stream>>>(coor2T, f4T, d_out, flag);
}

// Round 4
// 1520.206 us; speedup vs baseline: 2.0059x; 1.2134x over previous
//
#include <hip/hip_runtime.h>
#include <cstdint>

typedef unsigned int uint;
typedef unsigned short u16;

#define DEV __device__ __forceinline__

DEV float bf2f(u16 u) { return __uint_as_float(((uint)u) << 16); }
DEV u16 f2bf(float f) {
    uint x = __float_as_uint(f);
    return (u16)((x + 0x7fffu + ((x >> 16) & 1u)) >> 16);
}

// ---------------------------------------------------------------------------
// dtype detect: flag=1 if x buffer is bf16, 0 if f32.
// ---------------------------------------------------------------------------
__global__ void detect_kernel(const u16* __restrict__ x, int* __restrict__ flag)
{
    __shared__ int cnt[256];
    int t = threadIdx.x, good = 0;
#pragma unroll
    for (int i = 0; i < 8; ++i) {
        int s = t * 8 + i;
        u16 u = x[s * 37];
        int e = (u >> 7) & 0xFF;
        good += (e >= 90 && e <= 150) ? 1 : 0;
    }
    cnt[t] = good;
    __syncthreads();
    if (t == 0) {
        int s = 0;
        for (int i = 0; i < 256; ++i) s += cnt[i];
        flag[0] = (s >= 1741) ? 1 : 0;
    }
}

// ---------------------------------------------------------------------------
// convert all weight/param buffers to f32 in workspace (flag-branched).
// ---------------------------------------------------------------------------
struct InPtrs { const void* p[14]; };

__global__ void convert_weights(InPtrs ptrs, const int* __restrict__ flag,
                                float* __restrict__ cw)
{
    const int cnt[14] = {24, 8, 512, 32, 32, 4096, 64, 64, 8192, 64, 64, 16384, 128, 128};
    int g = blockIdx.x * 256 + threadIdx.x;
    if (g >= 29792) return;
    int isbf = flag[0];
    int idx = g, b = 0;
    while (idx >= cnt[b]) { idx -= cnt[b]; ++b; }
    cw[g] = isbf ? bf2f(((const u16*)ptrs.p[b])[idx])
                 : ((const float*)ptrs.p[b])[idx];
}

// ---------------------------------------------------------------------------
// prep: x (B,3,N) -> coorT (B,N,3) f32, f0 = w_in*x + b_in as (B,N,8) f32.
// ---------------------------------------------------------------------------
__global__ void prep_kernel(const void* __restrict__ xv, const int* __restrict__ flag,
                            const float* __restrict__ cw, float* __restrict__ coorT,
                            float* __restrict__ f0, int B, int N)
{
    int p = blockIdx.x * blockDim.x + threadIdx.x;
    if (p >= B * N) return;
    int isbf = flag[0];
    int b = p / N, n = p % N;
    float c0, c1, c2;
    if (isbf) {
        const u16* x = (const u16*)xv;
        c0 = bf2f(x[(b * 3 + 0) * N + n]);
        c1 = bf2f(x[(b * 3 + 1) * N + n]);
        c2 = bf2f(x[(b * 3 + 2) * N + n]);
    } else {
        const float* x = (const float*)xv;
        c0 = x[(b * 3 + 0) * N + n];
        c1 = x[(b * 3 + 1) * N + n];
        c2 = x[(b * 3 + 2) * N + n];
    }
    coorT[p * 3 + 0] = c0; coorT[p * 3 + 1] = c1; coorT[p * 3 + 2] = c2;
    const float* w_in = cw;
    const float* b_in = cw + 24;
#pragma unroll
    for (int o = 0; o < 8; ++o) {
        float v = b_in[o];
        v = fmaf(w_in[o * 3 + 0], c0, v);
        v = fmaf(w_in[o * 3 + 1], c1, v);
        v = fmaf(w_in[o * 3 + 2], c2, v);
        f0[(size_t)p * 8 + o] = v;
    }
}

// ---------------------------------------------------------------------------
// knn: 64 queries per block; 4 waves split each 256-key tile 4-ways; partial
// top-16 lists lex-merged (d2, idx) in LDS. Exact-RN ops; set identical to
// full scan incl. lowest-index tie-break.
// ---------------------------------------------------------------------------
__global__ __launch_bounds__(256) void knn_kernel(
    const float* __restrict__ qxyz, const float* __restrict__ kxyz,
    int* __restrict__ idxout, int Nq, int Nk)
{
    __shared__ float4 kt[256];
    __shared__ float2 mrg[4][64][16];
    int b = blockIdx.y;
    int qloc = threadIdx.x & 63;
    int wave = threadIdx.x >> 6;
    int q = blockIdx.x * 64 + qloc;
    bool act = q < Nq;

    float qx = 0.f, qy = 0.f, qz = 0.f, qq = 0.f;
    if (act) {
        const float* qp = qxyz + (size_t)(b * Nq + q) * 3;
        qx = qp[0]; qy = qp[1]; qz = qp[2];
        qq = __fadd_rn(__fadd_rn(__fmul_rn(qx, qx), __fmul_rn(qy, qy)), __fmul_rn(qz, qz));
    }
    float bd[16]; int bi[16];
#pragma unroll
    for (int j = 0; j < 16; ++j) { bd[j] = 3.4e38f; bi[j] = 0; }

    for (int t0 = 0; t0 < Nk; t0 += 256) {
        {
            int i = threadIdx.x;
            const float* kp = kxyz + (size_t)(b * Nk + t0 + i) * 3;
            float kx = kp[0], ky = kp[1], kz = kp[2];
            float kn = __fadd_rn(__fadd_rn(__fmul_rn(kx, kx), __fmul_rn(ky, ky)), __fmul_rn(kz, kz));
            kt[i] = make_float4(kx, ky, kz, kn);
        }
        __syncthreads();
        if (act) {
            for (int i2 = 0; i2 < 64; ++i2) {
                int ii = wave * 64 + i2;
                float4 kv = kt[ii];
                float dot = __fadd_rn(__fadd_rn(__fmul_rn(qx, kv.x), __fmul_rn(qy, kv.y)),
                                      __fmul_rn(qz, kv.z));
                float d2 = __fsub_rn(__fadd_rn(qq, kv.w), __fmul_rn(2.0f, dot));
                if (d2 < bd[15]) {
                    int id = t0 + ii;
#pragma unroll
                    for (int j = 15; j >= 1; --j) {
                        bool up  = (d2 < bd[j - 1]);
                        bool chg = (d2 < bd[j]);
                        if (chg) { bd[j] = up ? bd[j - 1] : d2; bi[j] = up ? bi[j - 1] : id; }
                    }
                    if (d2 < bd[0]) { bd[0] = d2; bi[0] = id; }
                }
            }
        }
        __syncthreads();
    }
#pragma unroll
    for (int j = 0; j < 16; ++j)
        mrg[wave][qloc][j] = make_float2(bd[j], __int_as_float(bi[j]));
    __syncthreads();

    if (threadIdx.x < 64) {
        int qm = threadIdx.x;
        int qg = blockIdx.x * 64 + qm;
        if (qg < Nq) {
            int* op = idxout + (size_t)(b * Nq + qg) * 16;
            int p0 = 0, p1 = 0, p2 = 0, p3 = 0;
#pragma unroll 1
            for (int j = 0; j < 16; ++j) {
                float2 h0 = mrg[0][qm][p0], h1 = mrg[1][qm][p1];
                float2 h2 = mrg[2][qm][p2], h3 = mrg[3][qm][p3];
                float bdv = h0.x; int biv = __float_as_int(h0.y); int w_ = 0;
                int i1 = __float_as_int(h1.y);
                if (h1.x < bdv || (h1.x == bdv && i1 < biv)) { bdv = h1.x; biv = i1; w_ = 1; }
                int i2v = __float_as_int(h2.y);
                if (h2.x < bdv || (h2.x == bdv && i2v < biv)) { bdv = h2.x; biv = i2v; w_ = 2; }
                int i3 = __float_as_int(h3.y);
                if (h3.x < bdv || (h3.x == bdv && i3 < biv)) { bdv = h3.x; biv = i3; w_ = 3; }
                op[j] = biv;
                p0 += (w_ == 0); p1 += (w_ == 1); p2 += (w_ == 2); p3 += (w_ == 3);
            }
        }
    }
}

// ---------------------------------------------------------------------------
// fps: LDS-staged cloud; coords+dist in registers; DPP (VALU-latency) wave
// argmax butterfly instead of ds_bpermute shuffles; ONE barrier per iteration
// (parity-double-buffered cross-wave slots, redundant final chain).
// Exact-RN math; argmax tie-break lowest index (total order -> tree-shape
// independent winner).
// ---------------------------------------------------------------------------
// pair-reduce DPP step: take (val,idx) from DPP-shuffled lanes, keep max val,
// tie -> min idx. old=self makes unsupplied lanes a harmless self-compare.
#define FPS_DPP_STEP(CTRL)                                                           \
    {                                                                                \
        float ov = __int_as_float(__builtin_amdgcn_update_dpp(                       \
            __float_as_int(bv), __float_as_int(bv), (CTRL), 0xf, 0xf, false));       \
        int oi = __builtin_amdgcn_update_dpp(bid, bid, (CTRL), 0xf, 0xf, false);     \
        bool t = (ov > bv) || (ov == bv && oi < bid);                                \
        bv = t ? ov : bv; bid = t ? oi : bid;                                        \
    }

#define FPS_CHAIN(A, B)                                                              \
    {                                                                                \
        float ov = (A); int oi = __float_as_int(B);                                  \
        bool t = (ov > v) || (ov == v && oi < ix);                                   \
        v = t ? ov : v; ix = t ? oi : ix;                                            \
    }

template<int PTS, int N>
__global__ __launch_bounds__(512) void fps_kernel(const float* __restrict__ xyz,
                                                  int* __restrict__ out, int npoint)
{
    __shared__ float sx[N], sy[N], sz[N];
    __shared__ alignas(16) float2 rp[2][8];
    int b = blockIdx.x, tid = threadIdx.x;
    int wave = tid >> 6, lane = tid & 63;
    float px[PTS], py[PTS], pz[PTS], dist[PTS];
#pragma unroll
    for (int i = 0; i < PTS; ++i) {
        int p = tid + i * 512;
        const float* pp = xyz + (size_t)(b * N + p) * 3;
        float x0 = pp[0], y0 = pp[1], z0 = pp[2];
        px[i] = x0; py[i] = y0; pz[i] = z0;
        sx[p] = x0; sy[p] = y0; sz[p] = z0;
        dist[i] = 1e10f;
    }
    __syncthreads();
    int far = 0;
    for (int it = 0; it < npoint; ++it) {
        if (tid == 0) out[b * npoint + it] = far;
        float cx = sx[far], cy = sy[far], cz = sz[far];
        float bv = -1.f; int bid = 0;
#pragma unroll
        for (int i = 0; i < PTS; ++i) {
            float dx = __fsub_rn(px[i], cx);
            float dy = __fsub_rn(py[i], cy);
            float dz = __fsub_rn(pz[i], cz);
            float d = __fadd_rn(__fadd_rn(__fmul_rn(dx, dx), __fmul_rn(dy, dy)), __fmul_rn(dz, dz));
            float nd = fminf(dist[i], d);
            dist[i] = nd;
            bool t = nd > bv;
            bv = t ? nd : bv; bid = t ? (tid + i * 512) : bid;
        }
        // wave argmax: xor1, xor2, quad-mix ror4+ror8, then bcast15/31 -> lane63
        FPS_DPP_STEP(0x0B1)   // quad_perm [1,0,3,2]
        FPS_DPP_STEP(0x04E)   // quad_perm [2,3,0,1]
        FPS_DPP_STEP(0x124)   // row_ror:4
        FPS_DPP_STEP(0x128)   // row_ror:8
        FPS_DPP_STEP(0x142)   // row_bcast15
        FPS_DPP_STEP(0x143)   // row_bcast31  -> lane 63 holds wave winner
        int par = it & 1;
        if (lane == 63) rp[par][wave] = make_float2(bv, __int_as_float(bid));
        __syncthreads();
        {
            const float4* rp4 = reinterpret_cast<const float4*>(&rp[par][0]);
            float4 a0 = rp4[0], a1 = rp4[1], a2 = rp4[2], a3 = rp4[3];
            float v = a0.x; int ix = __float_as_int(a0.y);
            FPS_CHAIN(a0.z, a0.w)
            FPS_CHAIN(a1.x, a1.y)
            FPS_CHAIN(a1.z, a1.w)
            FPS_CHAIN(a2.x, a2.y)
            FPS_CHAIN(a2.z, a2.w)
            FPS_CHAIN(a3.x, a3.y)
            FPS_CHAIN(a3.z, a3.w)
            far = ix;
        }
    }
}

// ---------------------------------------------------------------------------
// gather: coorD/fD[m] = coorS/fS[fidx[m]]
// ---------------------------------------------------------------------------
__global__ void gather_kernel(const float* __restrict__ coorS, const float* __restrict__ fS,
                              const int* __restrict__ fidx, float* __restrict__ coorD,
                              float* __restrict__ fD, int Ns, int M, int C)
{
    int b = blockIdx.y;
    int m = blockIdx.x * blockDim.x + threadIdx.x;
    if (m >= M) return;
    int j = fidx[b * M + m];
#pragma unroll
    for (int c = 0; c < 3; ++c)
        coorD[((size_t)b * M + m) * 3 + c] = coorS[((size_t)b * Ns + j) * 3 + c];
    for (int c = 0; c < C; ++c)
        fD[((size_t)b * M + m) * C + c] = fS[((size_t)b * Ns + j) * C + c];
}

// ---------------------------------------------------------------------------
// edge-conv stats: wave per query; lane per out-channel; edge feats in LDS.
// ---------------------------------------------------------------------------
template<int C_IN, int C_OUT>
__global__ __launch_bounds__(256) void edge_conv_stats(
    const float* __restrict__ fq, const float* __restrict__ fk, const int* __restrict__ idx,
    const float* __restrict__ w, float* __restrict__ partials, int Nq, int Nk)
{
    constexpr int K = 16, E = 2 * C_IN, GC = C_OUT / 4;
    constexpr int ITERS = (C_OUT + 63) / 64;
    __shared__ alignas(16) float edge[4][K][E];
    __shared__ int nidx[4][K];
    __shared__ float gsum[4][4][2];

    int wave = threadIdx.x >> 6, lane = threadIdx.x & 63;
    int nqc = Nq >> 2;
    int b = blockIdx.y, chunk = blockIdx.x;
    int q = chunk * 4 + wave;

    const float* xqr = fq + (size_t)(b * Nq + q) * C_IN;
    if (lane < K) nidx[wave][lane] = idx[(size_t)(b * Nq + q) * K + lane];
    for (int t = lane; t < K * E; t += 64) {
        int k = t / E, c = t % E;
        int j = nidx[wave][k];
        float v;
        if (c < C_IN) v = fk[(size_t)(b * Nk + j) * C_IN + c] - xqr[c];
        else          v = xqr[c - C_IN];
        edge[wave][k][c] = v;
    }
    __syncthreads();

#pragma unroll
    for (int itr = 0; itr < ITERS; ++itr) {
        int oc = lane + 64 * itr;
        float s = 0.f, ss = 0.f;
        if (oc < C_OUT) {
            float v[K];
#pragma unroll
            for (int k2 = 0; k2 < K; ++k2) v[k2] = 0.f;
            const float* wr = w + (size_t)oc * E;
            for (int c = 0; c < E; c += 4) {
                float4 wv = *reinterpret_cast<const float4*>(wr + c);
#pragma unroll
                for (int k2 = 0; k2 < K; ++k2) {
                    const float4 e4 = *reinterpret_cast<const float4*>(&edge[wave][k2][c]);
                    v[k2] = fmaf(wv.x, e4.x, v[k2]);
                    v[k2] = fmaf(wv.y, e4.y, v[k2]);
                    v[k2] = fmaf(wv.z, e4.z, v[k2]);
                    v[k2] = fmaf(wv.w, e4.w, v[k2]);
                }
            }
#pragma unroll
            for (int k2 = 0; k2 < K; ++k2) { s += v[k2]; ss = fmaf(v[k2], v[k2], ss); }
        }
#pragma unroll
        for (int m2 = 1; m2 < GC; m2 <<= 1) { s += __shfl_xor(s, m2); ss += __shfl_xor(ss, m2); }
        if (oc < C_OUT && (oc & (GC - 1)) == 0) {
            gsum[wave][oc / GC][0] = s; gsum[wave][oc / GC][1] = ss;
        }
    }
    __syncthreads();
    if (threadIdx.x < 4) {
        int g = threadIdx.x;
        float s  = ((gsum[0][g][0] + gsum[1][g][0]) + gsum[2][g][0]) + gsum[3][g][0];
        float ss = ((gsum[0][g][1] + gsum[1][g][1]) + gsum[2][g][1]) + gsum[3][g][1];
        size_t pi = ((size_t)(b * 4 + g) * nqc + chunk) * 2;
        partials[pi] = s; partials[pi + 1] = ss;
    }
}

// gn_finalize: 256 threads, 8 lanes per (b,g)-stat, shuffle reduce.
__global__ void gn_finalize(const float* __restrict__ partials, float* __restrict__ stats,
                            int nchunk, float inv_cnt)
{
    int i = threadIdx.x >> 3;       // stat id 0..31
    int sl = threadIdx.x & 7;       // sub-lane
    float s = 0.f, ss = 0.f;
    for (int c = sl; c < nchunk; c += 8) {
        s  += partials[((size_t)i * nchunk + c) * 2];
        ss += partials[((size_t)i * nchunk + c) * 2 + 1];
    }
#pragma unroll
    for (int m = 1; m < 8; m <<= 1) { s += __shfl_xor(s, m); ss += __shfl_xor(ss, m); }
    if (sl == 0) {
        float mean = s * inv_cnt;
        float var = fmaf(-mean, mean, ss * inv_cnt);
        stats[i * 2] = mean;
        stats[i * 2 + 1] = 1.0f / sqrtf(var + 1e-5f);
    }
}

// ---------------------------------------------------------------------------
// edge-conv apply: conv -> GN(normalize) -> leaky(0.2) -> max over K=16.
// ---------------------------------------------------------------------------
template<int C_IN, int C_OUT>
__global__ __launch_bounds__(256) void edge_conv_apply(
    const float* __restrict__ fq, const float* __restrict__ fk, const int* __restrict__ idx,
    const float* __restrict__ stats, const float* __restrict__ w,
    const float* __restrict__ gamma, const float* __restrict__ beta,
    float* __restrict__ outp, int Nq, int Nk)
{
    constexpr int K = 16, E = 2 * C_IN, GC = C_OUT / 4;
    constexpr int ITERS = (C_OUT + 63) / 64;
    __shared__ alignas(16) float edge[4][K][E];
    __shared__ int nidx[4][K];

    int wave = threadIdx.x >> 6, lane = threadIdx.x & 63;
    int b = blockIdx.y, chunk = blockIdx.x;
    int q = chunk * 4 + wave;

    const float* xqr = fq + (size_t)(b * Nq + q) * C_IN;
    if (lane < K) nidx[wave][lane] = idx[(size_t)(b * Nq + q) * K + lane];
    for (int t = lane; t < K * E; t += 64) {
        int k = t / E, c = t % E;
        int j = nidx[wave][k];
        float v;
        if (c < C_IN) v = fk[(size_t)(b * Nk + j) * C_IN + c] - xqr[c];
        else          v = xqr[c - C_IN];
        edge[wave][k][c] = v;
    }
    __syncthreads();

#pragma unroll
    for (int itr = 0; itr < ITERS; ++itr) {
        int oc = lane + 64 * itr;
        if (oc < C_OUT) {
            float v[K];
#pragma unroll
            for (int k2 = 0; k2 < K; ++k2) v[k2] = 0.f;
            const float* wr = w + (size_t)oc * E;
            for (int c = 0; c < E; c += 4) {
                float4 wv = *reinterpret_cast<const float4*>(wr + c);
#pragma unroll
                for (int k2 = 0; k2 < K; ++k2) {
                    const float4 e4 = *reinterpret_cast<const float4*>(&edge[wave][k2][c]);
                    v[k2] = fmaf(wv.x, e4.x, v[k2]);
                    v[k2] = fmaf(wv.y, e4.y, v[k2]);
                    v[k2] = fmaf(wv.z, e4.z, v[k2]);
                    v[k2] = fmaf(wv.w, e4.w, v[k2]);
                }
            }
            int g = oc / GC;
            float mean = stats[(b * 4 + g) * 2 + 0];
            float rstd = stats[(b * 4 + g) * 2 + 1];
            float ga = gamma[oc], be = beta[oc];
            float m = -3.4e38f;
#pragma unroll
            for (int k2 = 0; k2 < K; ++k2) {
                float y = fmaf((v[k2] - mean) * rstd, ga, be);
                y = (y >= 0.f) ? y : 0.2f * y;
                m = fmaxf(m, y);
            }
            outp[(size_t)(b * Nq + q) * C_OUT + oc] = m;
        }
    }
}

// ---------------------------------------------------------------------------
// write_out: out = [coor (B,3,128), f (B,128,128)], dtype per flag.
// ---------------------------------------------------------------------------
__global__ void write_out_kernel(const float* __restrict__ coor2T, const float* __restrict__ f4T,
                                 void* __restrict__ outv, const int* __restrict__ flag)
{
    int i = blockIdx.x * blockDim.x + threadIdx.x;
    if (i >= 134144) return;
    float v;
    if (i < 3072) {
        int b = i / 384, r = i % 384;
        int c = r / 128, n = r % 128;
        v = coor2T[((size_t)b * 128 + n) * 3 + c];
    } else {
        int jj = i - 3072;
        int b = jj / 16384, r = jj % 16384;
        int c = r / 128, qn = r % 128;
        v = f4T[((size_t)b * 128 + qn) * 128 + c];
    }
    if (flag[0]) ((u16*)outv)[i] = f2bf(v);
    else         ((float*)outv)[i] = v;
}

// ---------------------------------------------------------------------------
extern "C" void kernel_launch(void* const* d_in, const int* in_sizes, int n_in,
                              void* d_out, int out_size, void* d_ws, size_t ws_size,
                              hipStream_t stream)
{
    (void)in_sizes; (void)n_in; (void)out_size; (void)ws_size;
    constexpr int B = 8, N = 4096, M1 = 512, M2 = 128;

    float* fbase   = (float*)d_ws;
    float* coorT   = fbase;                  // 98304
    float* f0T     = coorT + 98304;          // 262144
    float* f1T     = f0T + 262144;           // 1048576
    float* f2T     = f1T + 1048576;          // 262144
    float* f3T     = f2T + 262144;           // 262144
    float* f4T     = f3T + 262144;           // 131072
    float* coor1T  = f4T + 131072;           // 12288
    float* coor2T  = coor1T + 12288;         // 3072
    float* fq2T    = coor2T + 3072;          // 131072
    float* fq4T    = fq2T + 131072;          // 65536
    float* statsb  = fq4T + 65536;           // 256
    float* partials= statsb + 256;           // 65536
    float* cw      = partials + 65536;       // 29792 (+pad to 29796)
    int* ibase = (int*)(cw + 29796);
    int* idx1 = ibase;                       // 524288
    int* idx2 = idx1 + 524288;               // 65536
    int* idx3 = idx2 + 65536;                // 65536
    int* idx4 = idx3 + 65536;                // 16384
    int* fps1 = idx4 + 16384;                // 4096
    int* fps2 = fps1 + 4096;                 // 1024
    int* flag = fps2 + 1024;                 // 1

    const float* w1c  = cw + 32;
    const float* g1c  = cw + 544;
    const float* be1c = cw + 576;
    const float* w2c  = cw + 608;
    const float* g2c  = cw + 4704;
    const float* be2c = cw + 4768;
    const float* w3c  = cw + 4832;
    const float* g3c  = cw + 13024;
    const float* be3c = cw + 13088;
    const float* w4c  = cw + 13152;
    const float* g4c  = cw + 29536;
    const float* be4c = cw + 29664;

    detect_kernel<<<1, 256, 0, stream>>>((const u16*)d_in[0], flag);
    InPtrs ptrs;
    for (int i = 0; i < 14; ++i) ptrs.p[i] = d_in[i + 2];
    convert_weights<<<117, 256, 0, stream>>>(ptrs, flag, cw);

    prep_kernel<<<dim3((B * N + 255) / 256), 256, 0, stream>>>(d_in[0], flag, cw, coorT, f0T, B, N);

    // stage 1
    knn_kernel<<<dim3(N / 64, B), 256, 0, stream>>>(coorT, coorT, idx1, N, N);
    edge_conv_stats<8, 32><<<dim3(N / 4, B), 256, 0, stream>>>(f0T, f0T, idx1, w1c, partials, N, N);
    gn_finalize<<<1, 256, 0, stream>>>(partials, statsb + 0, N / 4, 1.0f / (float)(N * 16 * 8));
    edge_conv_apply<8, 32><<<dim3(N / 4, B), 256, 0, stream>>>(f0T, f0T, idx1, statsb + 0, w1c, g1c, be1c, f1T, N, N);

    // fps 4096 -> 512 + gather
    fps_kernel<8, 4096><<<B, 512, 0, stream>>>(coorT, fps1, M1);
    gather_kernel<<<dim3((M1 + 255) / 256, B), 256, 0, stream>>>(coorT, f1T, fps1, coor1T, fq2T, N, M1, 32);

    // stage 2
    knn_kernel<<<dim3(M1 / 64, B), 256, 0, stream>>>(coor1T, coorT, idx2, M1, N);
    edge_conv_stats<32, 64><<<dim3(M1 / 4, B), 256, 0, stream>>>(fq2T, f1T, idx2, w2c, partials, M1, N);
    gn_finalize<<<1, 256, 0, stream>>>(partials, statsb + 64, M1 / 4, 1.0f / (float)(M1 * 16 * 16));
    edge_conv_apply<32, 64><<<dim3(M1 / 4, B), 256, 0, stream>>>(fq2T, f1T, idx2, statsb + 64, w2c, g2c, be2c, f2T, M1, N);

    // stage 3
    knn_kernel<<<dim3(M1 / 64, B), 256, 0, stream>>>(coor1T, coor1T, idx3, M1, M1);
    edge_conv_stats<64, 64><<<dim3(M1 / 4, B), 256, 0, stream>>>(f2T, f2T, idx3, w3c, partials, M1, M1);
    gn_finalize<<<1, 256, 0, stream>>>(partials, statsb + 128, M1 / 4, 1.0f / (float)(M1 * 16 * 16));
    edge_conv_apply<64, 64><<<dim3(M1 / 4, B), 256, 0, stream>>>(f2T, f2T, idx3, statsb + 128, w3c, g3c, be3c, f3T, M1, M1);

    // fps 512 -> 128 + gather
    fps_kernel<1, 512><<<B, 512, 0, stream>>>(coor1T, fps2, M2);
    gather_kernel<<<dim3(1, B), 256, 0, stream>>>(coor1T, f3T, fps2, coor2T, fq4T, M1, M2, 64);

    // stage 4
    knn_kernel<<<dim3((M2 + 63) / 64, B), 256, 0, stream>>>(coor2T, coor1T, idx4, M2, M1);
    edge_conv_stats<64, 128><<<dim3(M2 / 4, B), 256, 0, stream>>>(fq4T, f3T, idx4, w4c, partials, M2, M1);
    gn_finalize<<<1, 256, 0, stream>>>(partials, statsb + 192, M2 / 4, 1.0f / (float)(M2 * 16 * 32));
    edge_conv_apply<64, 128><<<dim3(M2 / 4, B), 256, 0, stream>>>(fq4T, f3T, idx4, statsb + 192, w4c, g4c, be4c, f4T, M2, M1);

    write_out_kernel<<<(134144 + 255) / 256, 256, 0, stream>>>(coor2T, f4T, d_out, flag);
}

// Round 6
// 1467.154 us; speedup vs baseline: 2.0785x; 1.0362x over previous
//
#include <hip/hip_runtime.h>
#include <cstdint>

typedef unsigned int uint;
typedef unsigned short u16;

#define DEV __device__ __forceinline__

DEV float bf2f(u16 u) { return __uint_as_float(((uint)u) << 16); }
DEV u16 f2bf(float f) {
    uint x = __float_as_uint(f);
    return (u16)((x + 0x7fffu + ((x >> 16) & 1u)) >> 16);
}

// ---------------------------------------------------------------------------
// dtype detect: flag=1 if x buffer is bf16, 0 if f32.
// ---------------------------------------------------------------------------
__global__ void detect_kernel(const u16* __restrict__ x, int* __restrict__ flag)
{
    __shared__ int cnt[256];
    int t = threadIdx.x, good = 0;
#pragma unroll
    for (int i = 0; i < 8; ++i) {
        int s = t * 8 + i;
        u16 u = x[s * 37];
        int e = (u >> 7) & 0xFF;
        good += (e >= 90 && e <= 150) ? 1 : 0;
    }
    cnt[t] = good;
    __syncthreads();
    if (t == 0) {
        int s = 0;
        for (int i = 0; i < 256; ++i) s += cnt[i];
        flag[0] = (s >= 1741) ? 1 : 0;
    }
}

// ---------------------------------------------------------------------------
// convert all weight/param buffers to f32 in workspace (flag-branched).
// ---------------------------------------------------------------------------
struct InPtrs { const void* p[14]; };

__global__ void convert_weights(InPtrs ptrs, const int* __restrict__ flag,
                                float* __restrict__ cw)
{
    const int cnt[14] = {24, 8, 512, 32, 32, 4096, 64, 64, 8192, 64, 64, 16384, 128, 128};
    int g = blockIdx.x * 256 + threadIdx.x;
    if (g >= 29792) return;
    int isbf = flag[0];
    int idx = g, b = 0;
    while (idx >= cnt[b]) { idx -= cnt[b]; ++b; }
    cw[g] = isbf ? bf2f(((const u16*)ptrs.p[b])[idx])
                 : ((const float*)ptrs.p[b])[idx];
}

// ---------------------------------------------------------------------------
// prep: x (B,3,N) -> coorT (B,N,3) f32, f0 = w_in*x + b_in as (B,N,8) f32.
// ---------------------------------------------------------------------------
__global__ void prep_kernel(const void* __restrict__ xv, const int* __restrict__ flag,
                            const float* __restrict__ cw, float* __restrict__ coorT,
                            float* __restrict__ f0, int B, int N)
{
    int p = blockIdx.x * blockDim.x + threadIdx.x;
    if (p >= B * N) return;
    int isbf = flag[0];
    int b = p / N, n = p % N;
    float c0, c1, c2;
    if (isbf) {
        const u16* x = (const u16*)xv;
        c0 = bf2f(x[(b * 3 + 0) * N + n]);
        c1 = bf2f(x[(b * 3 + 1) * N + n]);
        c2 = bf2f(x[(b * 3 + 2) * N + n]);
    } else {
        const float* x = (const float*)xv;
        c0 = x[(b * 3 + 0) * N + n];
        c1 = x[(b * 3 + 1) * N + n];
        c2 = x[(b * 3 + 2) * N + n];
    }
    coorT[p * 3 + 0] = c0; coorT[p * 3 + 1] = c1; coorT[p * 3 + 2] = c2;
    const float* w_in = cw;
    const float* b_in = cw + 24;
#pragma unroll
    for (int o = 0; o < 8; ++o) {
        float v = b_in[o];
        v = fmaf(w_in[o * 3 + 0], c0, v);
        v = fmaf(w_in[o * 3 + 1], c1, v);
        v = fmaf(w_in[o * 3 + 2], c2, v);
        f0[(size_t)p * 8 + o] = v;
    }
}

// ---------------------------------------------------------------------------
// knn: 64 queries per block; 4 waves split each 256-key tile 4-ways; partial
// top-16 lists lex-merged (d2, idx) in LDS. Exact-RN ops; set identical to
// full scan incl. lowest-index tie-break.
// ---------------------------------------------------------------------------
__global__ __launch_bounds__(256) void knn_kernel(
    const float* __restrict__ qxyz, const float* __restrict__ kxyz,
    int* __restrict__ idxout, int Nq, int Nk)
{
    __shared__ float4 kt[256];
    __shared__ float2 mrg[4][64][16];
    int b = blockIdx.y;
    int qloc = threadIdx.x & 63;
    int wave = threadIdx.x >> 6;
    int q = blockIdx.x * 64 + qloc;
    bool act = q < Nq;

    float qx = 0.f, qy = 0.f, qz = 0.f, qq = 0.f;
    if (act) {
        const float* qp = qxyz + (size_t)(b * Nq + q) * 3;
        qx = qp[0]; qy = qp[1]; qz = qp[2];
        qq = __fadd_rn(__fadd_rn(__fmul_rn(qx, qx), __fmul_rn(qy, qy)), __fmul_rn(qz, qz));
    }
    float bd[16]; int bi[16];
#pragma unroll
    for (int j = 0; j < 16; ++j) { bd[j] = 3.4e38f; bi[j] = 0; }

    for (int t0 = 0; t0 < Nk; t0 += 256) {
        {
            int i = threadIdx.x;
            const float* kp = kxyz + (size_t)(b * Nk + t0 + i) * 3;
            float kx = kp[0], ky = kp[1], kz = kp[2];
            float kn = __fadd_rn(__fadd_rn(__fmul_rn(kx, kx), __fmul_rn(ky, ky)), __fmul_rn(kz, kz));
            kt[i] = make_float4(kx, ky, kz, kn);
        }
        __syncthreads();
        if (act) {
            for (int i2 = 0; i2 < 64; ++i2) {
                int ii = wave * 64 + i2;
                float4 kv = kt[ii];
                float dot = __fadd_rn(__fadd_rn(__fmul_rn(qx, kv.x), __fmul_rn(qy, kv.y)),
                                      __fmul_rn(qz, kv.z));
                float d2 = __fsub_rn(__fadd_rn(qq, kv.w), __fmul_rn(2.0f, dot));
                if (d2 < bd[15]) {
                    int id = t0 + ii;
#pragma unroll
                    for (int j = 15; j >= 1; --j) {
                        bool up  = (d2 < bd[j - 1]);
                        bool chg = (d2 < bd[j]);
                        if (chg) { bd[j] = up ? bd[j - 1] : d2; bi[j] = up ? bi[j - 1] : id; }
                    }
                    if (d2 < bd[0]) { bd[0] = d2; bi[0] = id; }
                }
            }
        }
        __syncthreads();
    }
#pragma unroll
    for (int j = 0; j < 16; ++j)
        mrg[wave][qloc][j] = make_float2(bd[j], __int_as_float(bi[j]));
    __syncthreads();

    if (threadIdx.x < 64) {
        int qm = threadIdx.x;
        int qg = blockIdx.x * 64 + qm;
        if (qg < Nq) {
            int* op = idxout + (size_t)(b * Nq + qg) * 16;
            int p0 = 0, p1 = 0, p2 = 0, p3 = 0;
#pragma unroll 1
            for (int j = 0; j < 16; ++j) {
                float2 h0 = mrg[0][qm][p0], h1 = mrg[1][qm][p1];
                float2 h2 = mrg[2][qm][p2], h3 = mrg[3][qm][p3];
                float bdv = h0.x; int biv = __float_as_int(h0.y); int w_ = 0;
                int i1 = __float_as_int(h1.y);
                if (h1.x < bdv || (h1.x == bdv && i1 < biv)) { bdv = h1.x; biv = i1; w_ = 1; }
                int i2v = __float_as_int(h2.y);
                if (h2.x < bdv || (h2.x == bdv && i2v < biv)) { bdv = h2.x; biv = i2v; w_ = 2; }
                int i3 = __float_as_int(h3.y);
                if (h3.x < bdv || (h3.x == bdv && i3 < biv)) { bdv = h3.x; biv = i3; w_ = 3; }
                op[j] = biv;
                p0 += (w_ == 0); p1 += (w_ == 1); p2 += (w_ == 2); p3 += (w_ == 3);
            }
        }
    }
}

// ---------------------------------------------------------------------------
// fps: LDS-staged cloud (float4); coords+dist in registers; DPP wave argmax;
// ONE barrier per iteration; NO global store in the loop (register capture,
// coalesced epilogue write) -- avoids the per-barrier vmcnt(0) drain of a
// pending HBM store. Cross-wave merge: lane63 ds_write_b64 -> all lanes
// ds_read_b64 rp[par][lane&7] -> 3-step DPP -> winner in every lane.
// Exact-RN math; argmax tie-break lowest index.
// ---------------------------------------------------------------------------
#define FPS_DPP_STEP(CTRL)                                                           \
    {                                                                                \
        float ov = __int_as_float(__builtin_amdgcn_update_dpp(                       \
            __float_as_int(bv), __float_as_int(bv), (CTRL), 0xf, 0xf, false));       \
        int oi = __builtin_amdgcn_update_dpp(bid, bid, (CTRL), 0xf, 0xf, false);     \
        bool t = (ov > bv) || (ov == bv && oi < bid);                                \
        bv = t ? ov : bv; bid = t ? oi : bid;                                        \
    }

#define FPS_MRG_STEP(CTRL)                                                           \
    {                                                                                \
        float ov = __int_as_float(__builtin_amdgcn_update_dpp(                       \
            __float_as_int(mv), __float_as_int(mv), (CTRL), 0xf, 0xf, false));       \
        int oi = __builtin_amdgcn_update_dpp(mi, mi, (CTRL), 0xf, 0xf, false);       \
        bool t = (ov > mv) || (ov == mv && oi < mi);                                 \
        mv = t ? ov : mv; mi = t ? oi : mi;                                          \
    }

template<int PTS, int N>
__global__ __launch_bounds__(512) void fps_kernel(const float* __restrict__ xyz,
                                                  int* __restrict__ out, int npoint)
{
    __shared__ float4 sxyz[N];
    __shared__ alignas(16) float2 rp[2][8];
    int b = blockIdx.x, tid = threadIdx.x;
    int wave = tid >> 6, lane = tid & 63;
    float px[PTS], py[PTS], pz[PTS], dist[PTS];
#pragma unroll
    for (int i = 0; i < PTS; ++i) {
        int p = tid + i * 512;
        const float* pp = xyz + (size_t)(b * N + p) * 3;
        float x0 = pp[0], y0 = pp[1], z0 = pp[2];
        px[i] = x0; py[i] = y0; pz[i] = z0;
        sxyz[p] = make_float4(x0, y0, z0, 0.f);
        dist[i] = 1e10f;
    }
    __syncthreads();
    int far = 0;
    int myfar = 0;
    for (int it = 0; it < npoint; ++it) {
        if (it == tid) myfar = far;          // register capture, no global store
        float4 cv = sxyz[far];
        float cx = cv.x, cy = cv.y, cz = cv.z;
        float bv = -1.f; int bid = 0;
#pragma unroll
        for (int i = 0; i < PTS; ++i) {
            float dx = __fsub_rn(px[i], cx);
            float dy = __fsub_rn(py[i], cy);
            float dz = __fsub_rn(pz[i], cz);
            float d = __fadd_rn(__fadd_rn(__fmul_rn(dx, dx), __fmul_rn(dy, dy)), __fmul_rn(dz, dz));
            float nd = fminf(dist[i], d);
            dist[i] = nd;
            bool t = nd > bv;
            bv = t ? nd : bv; bid = t ? (tid + i * 512) : bid;
        }
        // wave argmax -> lane 63
        FPS_DPP_STEP(0x0B1)   // quad_perm [1,0,3,2]
        FPS_DPP_STEP(0x04E)   // quad_perm [2,3,0,1]
        FPS_DPP_STEP(0x124)   // row_ror:4
        FPS_DPP_STEP(0x128)   // row_ror:8
        FPS_DPP_STEP(0x142)   // row_bcast15
        FPS_DPP_STEP(0x143)   // row_bcast31
        int par = it & 1;
        if (lane == 63) rp[par][wave] = make_float2(bv, __int_as_float(bid));
        __syncthreads();
        // cross-wave merge: every lane reads one of the 8 entries (dup x8),
        // 3-step DPP network leaves the winner in every lane.
        {
            float2 e = rp[par][lane & 7];
            float mv = e.x; int mi = __float_as_int(e.y);
            FPS_MRG_STEP(0x0B1)   // xor1
            FPS_MRG_STEP(0x04E)   // xor2
            FPS_MRG_STEP(0x124)   // row_ror:4 (complementary quad; dups make it total)
            far = __builtin_amdgcn_readfirstlane(mi);
        }
    }
    if (tid < npoint) out[b * npoint + tid] = myfar;
}

// ---------------------------------------------------------------------------
// gather: coorD/fD[m] = coorS/fS[fidx[m]]
// ---------------------------------------------------------------------------
__global__ void gather_kernel(const float* __restrict__ coorS, const float* __restrict__ fS,
                              const int* __restrict__ fidx, float* __restrict__ coorD,
                              float* __restrict__ fD, int Ns, int M, int C)
{
    int b = blockIdx.y;
    int m = blockIdx.x * blockDim.x + threadIdx.x;
    if (m >= M) return;
    int j = fidx[b * M + m];
#pragma unroll
    for (int c = 0; c < 3; ++c)
        coorD[((size_t)b * M + m) * 3 + c] = coorS[((size_t)b * Ns + j) * 3 + c];
    for (int c = 0; c < C; ++c)
        fD[((size_t)b * M + m) * C + c] = fS[((size_t)b * Ns + j) * C + c];
}

// ---------------------------------------------------------------------------
// edge-conv stats: wave per query; lane per out-channel; edge feats in LDS.
// ---------------------------------------------------------------------------
template<int C_IN, int C_OUT>
__global__ __launch_bounds__(256) void edge_conv_stats(
    const float* __restrict__ fq, const float* __restrict__ fk, const int* __restrict__ idx,
    const float* __restrict__ w, float* __restrict__ partials, int Nq, int Nk)
{
    constexpr int K = 16, E = 2 * C_IN, GC = C_OUT / 4;
    constexpr int ITERS = (C_OUT + 63) / 64;
    __shared__ alignas(16) float edge[4][K][E];
    __shared__ int nidx[4][K];
    __shared__ float gsum[4][4][2];

    int wave = threadIdx.x >> 6, lane = threadIdx.x & 63;
    int nqc = Nq >> 2;
    int b = blockIdx.y, chunk = blockIdx.x;
    int q = chunk * 4 + wave;

    const float* xqr = fq + (size_t)(b * Nq + q) * C_IN;
    if (lane < K) nidx[wave][lane] = idx[(size_t)(b * Nq + q) * K + lane];
    for (int t = lane; t < K * E; t += 64) {
        int k = t / E, c = t % E;
        int j = nidx[wave][k];
        float v;
        if (c < C_IN) v = fk[(size_t)(b * Nk + j) * C_IN + c] - xqr[c];
        else          v = xqr[c - C_IN];
        edge[wave][k][c] = v;
    }
    __syncthreads();

#pragma unroll
    for (int itr = 0; itr < ITERS; ++itr) {
        int oc = lane + 64 * itr;
        float s = 0.f, ss = 0.f;
        if (oc < C_OUT) {
            float v[K];
#pragma unroll
            for (int k2 = 0; k2 < K; ++k2) v[k2] = 0.f;
            const float* wr = w + (size_t)oc * E;
            for (int c = 0; c < E; c += 4) {
                float4 wv = *reinterpret_cast<const float4*>(wr + c);
#pragma unroll
                for (int k2 = 0; k2 < K; ++k2) {
                    const float4 e4 = *reinterpret_cast<const float4*>(&edge[wave][k2][c]);
                    v[k2] = fmaf(wv.x, e4.x, v[k2]);
                    v[k2] = fmaf(wv.y, e4.y, v[k2]);
                    v[k2] = fmaf(wv.z, e4.z, v[k2]);
                    v[k2] = fmaf(wv.w, e4.w, v[k2]);
                }
            }
#pragma unroll
            for (int k2 = 0; k2 < K; ++k2) { s += v[k2]; ss = fmaf(v[k2], v[k2], ss); }
        }
#pragma unroll
        for (int m2 = 1; m2 < GC; m2 <<= 1) { s += __shfl_xor(s, m2); ss += __shfl_xor(ss, m2); }
        if (oc < C_OUT && (oc & (GC - 1)) == 0) {
            gsum[wave][oc / GC][0] = s; gsum[wave][oc / GC][1] = ss;
        }
    }
    __syncthreads();
    if (threadIdx.x < 4) {
        int g = threadIdx.x;
        float s  = ((gsum[0][g][0] + gsum[1][g][0]) + gsum[2][g][0]) + gsum[3][g][0];
        float ss = ((gsum[0][g][1] + gsum[1][g][1]) + gsum[2][g][1]) + gsum[3][g][1];
        size_t pi = ((size_t)(b * 4 + g) * nqc + chunk) * 2;
        partials[pi] = s; partials[pi + 1] = ss;
    }
}

// gn_finalize: 256 threads, 8 lanes per (b,g)-stat, shuffle reduce.
__global__ void gn_finalize(const float* __restrict__ partials, float* __restrict__ stats,
                            int nchunk, float inv_cnt)
{
    int i = threadIdx.x >> 3;       // stat id 0..31
    int sl = threadIdx.x & 7;       // sub-lane
    float s = 0.f, ss = 0.f;
    for (int c = sl; c < nchunk; c += 8) {
        s  += partials[((size_t)i * nchunk + c) * 2];
        ss += partials[((size_t)i * nchunk + c) * 2 + 1];
    }
#pragma unroll
    for (int m = 1; m < 8; m <<= 1) { s += __shfl_xor(s, m); ss += __shfl_xor(ss, m); }
    if (sl == 0) {
        float mean = s * inv_cnt;
        float var = fmaf(-mean, mean, ss * inv_cnt);
        stats[i * 2] = mean;
        stats[i * 2 + 1] = 1.0f / sqrtf(var + 1e-5f);
    }
}

// ---------------------------------------------------------------------------
// edge-conv apply: conv -> GN(normalize) -> leaky(0.2) -> max over K=16.
// ---------------------------------------------------------------------------
template<int C_IN, int C_OUT>
__global__ __launch_bounds__(256) void edge_conv_apply(
    const float* __restrict__ fq, const float* __restrict__ fk, const int* __restrict__ idx,
    const float* __restrict__ stats, const float* __restrict__ w,
    const float* __restrict__ gamma, const float* __restrict__ beta,
    float* __restrict__ outp, int Nq, int Nk)
{
    constexpr int K = 16, E = 2 * C_IN, GC = C_OUT / 4;
    constexpr int ITERS = (C_OUT + 63) / 64;
    __shared__ alignas(16) float edge[4][K][E];
    __shared__ int nidx[4][K];

    int wave = threadIdx.x >> 6, lane = threadIdx.x & 63;
    int b = blockIdx.y, chunk = blockIdx.x;
    int q = chunk * 4 + wave;

    const float* xqr = fq + (size_t)(b * Nq + q) * C_IN;
    if (lane < K) nidx[wave][lane] = idx[(size_t)(b * Nq + q) * K + lane];
    for (int t = lane; t < K * E; t += 64) {
        int k = t / E, c = t % E;
        int j = nidx[wave][k];
        float v;
        if (c < C_IN) v = fk[(size_t)(b * Nk + j) * C_IN + c] - xqr[c];
        else          v = xqr[c - C_IN];
        edge[wave][k][c] = v;
    }
    __syncthreads();

#pragma unroll
    for (int itr = 0; itr < ITERS; ++itr) {
        int oc = lane + 64 * itr;
        if (oc < C_OUT) {
            float v[K];
#pragma unroll
            for (int k2 = 0; k2 < K; ++k2) v[k2] = 0.f;
            const float* wr = w + (size_t)oc * E;
            for (int c = 0; c < E; c += 4) {
                float4 wv = *reinterpret_cast<const float4*>(wr + c);
#pragma unroll
                for (int k2 = 0; k2 < K; ++k2) {
                    const float4 e4 = *reinterpret_cast<const float4*>(&edge[wave][k2][c]);
                    v[k2] = fmaf(wv.x, e4.x, v[k2]);
                    v[k2] = fmaf(wv.y, e4.y, v[k2]);
                    v[k2] = fmaf(wv.z, e4.z, v[k2]);
                    v[k2] = fmaf(wv.w, e4.w, v[k2]);
                }
            }
            int g = oc / GC;
            float mean = stats[(b * 4 + g) * 2 + 0];
            float rstd = stats[(b * 4 + g) * 2 + 1];
            float ga = gamma[oc], be = beta[oc];
            float m = -3.4e38f;
#pragma unroll
            for (int k2 = 0; k2 < K; ++k2) {
                float y = fmaf((v[k2] - mean) * rstd, ga, be);
                y = (y >= 0.f) ? y : 0.2f * y;
                m = fmaxf(m, y);
            }
            outp[(size_t)(b * Nq + q) * C_OUT + oc] = m;
        }
    }
}

// ---------------------------------------------------------------------------
// write_out: out = [coor (B,3,128), f (B,128,128)], dtype per flag.
// ---------------------------------------------------------------------------
__global__ void write_out_kernel(const float* __restrict__ coor2T, const float* __restrict__ f4T,
                                 void* __restrict__ outv, const int* __restrict__ flag)
{
    int i = blockIdx.x * blockDim.x + threadIdx.x;
    if (i >= 134144) return;
    float v;
    if (i < 3072) {
        int b = i / 384, r = i % 384;
        int c = r / 128, n = r % 128;
        v = coor2T[((size_t)b * 128 + n) * 3 + c];
    } else {
        int jj = i - 3072;
        int b = jj / 16384, r = jj % 16384;
        int c = r / 128, qn = r % 128;
        v = f4T[((size_t)b * 128 + qn) * 128 + c];
    }
    if (flag[0]) ((u16*)outv)[i] = f2bf(v);
    else         ((float*)outv)[i] = v;
}

// ---------------------------------------------------------------------------
extern "C" void kernel_launch(void* const* d_in, const int* in_sizes, int n_in,
                              void* d_out, int out_size, void* d_ws, size_t ws_size,
                              hipStream_t stream)
{
    (void)in_sizes; (void)n_in; (void)out_size; (void)ws_size;
    constexpr int B = 8, N = 4096, M1 = 512, M2 = 128;

    float* fbase   = (float*)d_ws;
    float* coorT   = fbase;                  // 98304
    float* f0T     = coorT + 98304;          // 262144
    float* f1T     = f0T + 262144;           // 1048576
    float* f2T     = f1T + 1048576;          // 262144
    float* f3T     = f2T + 262144;           // 262144
    float* f4T     = f3T + 262144;           // 131072
    float* coor1T  = f4T + 131072;           // 12288
    float* coor2T  = coor1T + 12288;         // 3072
    float* fq2T    = coor2T + 3072;          // 131072
    float* fq4T    = fq2T + 131072;          // 65536
    float* statsb  = fq4T + 65536;           // 256
    float* partials= statsb + 256;           // 65536
    float* cw      = partials + 65536;       // 29792 (+pad to 29796)
    int* ibase = (int*)(cw + 29796);
    int* idx1 = ibase;                       // 524288
    int* idx2 = idx1 + 524288;               // 65536
    int* idx3 = idx2 + 65536;                // 65536
    int* idx4 = idx3 + 65536;                // 16384
    int* fps1 = idx4 + 16384;                // 4096
    int* fps2 = fps1 + 4096;                 // 1024
    int* flag = fps2 + 1024;                 // 1

    const float* w1c  = cw + 32;
    const float* g1c  = cw + 544;
    const float* be1c = cw + 576;
    const float* w2c  = cw + 608;
    const float* g2c  = cw + 4704;
    const float* be2c = cw + 4768;
    const float* w3c  = cw + 4832;
    const float* g3c  = cw + 13024;
    const float* be3c = cw + 13088;
    const float* w4c  = cw + 13152;
    const float* g4c  = cw + 29536;
    const float* be4c = cw + 29664;

    detect_kernel<<<1, 256, 0, stream>>>((const u16*)d_in[0], flag);
    InPtrs ptrs;
    for (int i = 0; i < 14; ++i) ptrs.p[i] = d_in[i + 2];
    convert_weights<<<117, 256, 0, stream>>>(ptrs, flag, cw);

    prep_kernel<<<dim3((B * N + 255) / 256), 256, 0, stream>>>(d_in[0], flag, cw, coorT, f0T, B, N);

    // stage 1
    knn_kernel<<<dim3(N / 64, B), 256, 0, stream>>>(coorT, coorT, idx1, N, N);
    edge_conv_stats<8, 32><<<dim3(N / 4, B), 256, 0, stream>>>(f0T, f0T, idx1, w1c, partials, N, N);
    gn_finalize<<<1, 256, 0, stream>>>(partials, statsb + 0, N / 4, 1.0f / (float)(N * 16 * 8));
    edge_conv_apply<8, 32><<<dim3(N / 4, B), 256, 0, stream>>>(f0T, f0T, idx1, statsb + 0, w1c, g1c, be1c, f1T, N, N);

    // fps 4096 -> 512 + gather
    fps_kernel<8, 4096><<<B, 512, 0, stream>>>(coorT, fps1, M1);
    gather_kernel<<<dim3((M1 + 255) / 256, B), 256, 0, stream>>>(coorT, f1T, fps1, coor1T, fq2T, N, M1, 32);

    // stage 2
    knn_kernel<<<dim3(M1 / 64, B), 256, 0, stream>>>(coor1T, coorT, idx2, M1, N);
    edge_conv_stats<32, 64><<<dim3(M1 / 4, B), 256, 0, stream>>>(fq2T, f1T, idx2, w2c, partials, M1, N);
    gn_finalize<<<1, 256, 0, stream>>>(partials, statsb + 64, M1 / 4, 1.0f / (float)(M1 * 16 * 16));
    edge_conv_apply<32, 64><<<dim3(M1 / 4, B), 256, 0, stream>>>(fq2T, f1T, idx2, statsb + 64, w2c, g2c, be2c, f2T, M1, N);

    // stage 3
    knn_kernel<<<dim3(M1 / 64, B), 256, 0, stream>>>(coor1T, coor1T, idx3, M1, M1);
    edge_conv_stats<64, 64><<<dim3(M1 / 4, B), 256, 0, stream>>>(f2T, f2T, idx3, w3c, partials, M1, M1);
    gn_finalize<<<1, 256, 0, stream>>>(partials, statsb + 128, M1 / 4, 1.0f / (float)(M1 * 16 * 16));
    edge_conv_apply<64, 64><<<dim3(M1 / 4, B), 256, 0, stream>>>(f2T, f2T, idx3, statsb + 128, w3c, g3c, be3c, f3T, M1, M1);

    // fps 512 -> 128 + gather
    fps_kernel<1, 512><<<B, 512, 0, stream>>>(coor1T, fps2, M2);
    gather_kernel<<<dim3(1, B), 256, 0, stream>>>(coor1T, f3T, fps2, coor2T, fq4T, M1, M2, 64);

    // stage 4
    knn_kernel<<<dim3((M2 + 63) / 64, B), 256, 0, stream>>>(coor2T, coor1T, idx4, M2, M1);
    edge_conv_stats<64, 128><<<dim3(M2 / 4, B), 256, 0, stream>>>(fq4T, f3T, idx4, w4c, partials, M2, M1);
    gn_finalize<<<1, 256, 0, stream>>>(partials, statsb + 192, M2 / 4, 1.0f / (float)(M2 * 16 * 32));
    edge_conv_apply<64, 128><<<dim3(M2 / 4, B), 256, 0, stream>>>(fq4T, f3T, idx4, statsb + 192, w4c, g4c, be4c, f4T, M2, M1);

    write_out_kernel<<<(134144 + 255) / 256, 256, 0, stream>>>(coor2T, f4T, d_out, flag);
}